// Round 1
// 3900.557 us; speedup vs baseline: 1.6544x; 1.6544x over previous
//
#include <hip/hip_runtime.h>
#include <hip/hip_bf16.h>

// problem constants
#define kT 8
#define kD 128
#define kH 8
#define kHD 16
#define kFF 512
#define kL 6
#define kNADM 2048
#define kNLAB 753
#define kNDRUG 4294
#define kE 16384

typedef __attribute__((ext_vector_type(8))) short short8;
typedef __attribute__((ext_vector_type(4))) float floatx4;

// round-to-nearest-even fp32 -> bf16 bits
__device__ __forceinline__ unsigned short f2b(float f) {
    unsigned x = __float_as_uint(f);
    unsigned r = (x + 0x7fffu + ((x >> 16) & 1u)) >> 16;
    return (unsigned short)r;
}

// ---------------- node projections ----------------
__global__ void proj_kernel(const float* __restrict__ x, int IK,
                            const float* __restrict__ w, const float* __restrict__ b,
                            const float* __restrict__ emb, const int* __restrict__ nid,
                            float* __restrict__ out) {
    int n = blockIdx.x, d = threadIdx.x;
    float acc = b[d];
    for (int k = 0; k < IK; ++k) acc += x[n * IK + k] * w[k * kD + d];
    if (emb) acc += emb[(long)nid[n] * kD + d];
    out[(long)n * kD + d] = acc;
}

// ---------------- GINE messages (both directions per edge) ----------------
__global__ void msg_kernel(const float* __restrict__ ex, int ek,
                           const int* __restrict__ src, const int* __restrict__ dst,
                           const float* __restrict__ we, const float* __restrict__ be,
                           const float* __restrict__ hS, long hSstride,
                           const float* __restrict__ hD, long hDstride,
                           float* __restrict__ msgDst, int Ndst,
                           float* __restrict__ msgSrc, int Nsrc) {
    int idx = blockIdx.x;
    int t = idx >> 14;
    int d = threadIdx.x;
    int s = src[idx], dd = dst[idx];
    const float* exp_ = ex + (long)idx * ek;
    float e = be[d];
    for (int k = 0; k < ek; ++k) e += exp_[k] * we[k * kD + d];
    float vf = hS[t * hSstride + (long)s * kD + d] + e; if (vf < 0.f) vf = 0.f;
    atomicAdd(&msgDst[((long)t * Ndst + dd) * kD + d], vf);
    float vr = hD[t * hDstride + (long)dd * kD + d] + e; if (vr < 0.f) vr = 0.f;
    atomicAdd(&msgSrc[((long)t * Nsrc + s) * kD + d], vr);
}

// ---------------- GNN dense: 16-row tiles, 2 rows x 4 cols per thread ----------------
__global__ __launch_bounds__(256) void gnn_dense16(const float* __restrict__ msg,
        const float* __restrict__ hin, long hinStride,
        const float* __restrict__ gw, const float* __restrict__ gb,
        int l, int type, float* __restrict__ out, int N, int rpt) {
    int t = blockIdx.x / rpt, rt = blockIdx.x % rpt;
    int r0 = rt * 16;
    int tid = threadIdx.x;
    int dq = tid & 31, rg = tid >> 5;      // cols dq*4..dq*4+3, rows rg*2, rg*2+1
    __shared__ float rows[16][kD];
    for (int x = tid; x < 16 * kD; x += 256) {
        int r = x >> 7, dd = x & 127;
        int n = r0 + r;
        rows[r][dd] = (n < N)
            ? msg[(((long)t * N + n) << 7) + dd] + hin[t * hinStride + ((long)n << 7) + dd]
            : 0.f;
    }
    __syncthreads();
    long wo = ((long)t * 2 + l) * 4 + type;
    const float* W = gw + (wo << 14);
    const float* bp = gb + (wo << 7) + dq * 4;
    float acc0[4], acc1[4];
#pragma unroll
    for (int j = 0; j < 4; ++j) { acc0[j] = bp[j]; acc1[j] = bp[j]; }
    const float* Rp0 = &rows[rg * 2][0];
    const float* Rp1 = &rows[rg * 2 + 1][0];
#pragma unroll 4
    for (int k = 0; k < kD; ++k) {
        float4 w = *(const float4*)&W[(k << 7) + dq * 4];
        float a0 = Rp0[k], a1 = Rp1[k];
        acc0[0] += a0 * w.x; acc0[1] += a0 * w.y; acc0[2] += a0 * w.z; acc0[3] += a0 * w.w;
        acc1[0] += a1 * w.x; acc1[1] += a1 * w.y; acc1[2] += a1 * w.z; acc1[3] += a1 * w.w;
    }
    int n0 = r0 + rg * 2;
    if (n0 < N) {
        float4 v;
        v.x = fmaxf(acc0[0], 0.f); v.y = fmaxf(acc0[1], 0.f);
        v.z = fmaxf(acc0[2], 0.f); v.w = fmaxf(acc0[3], 0.f);
        *(float4*)&out[(((long)t * N + n0) << 7) + dq * 4] = v;
    }
    if (n0 + 1 < N) {
        float4 v;
        v.x = fmaxf(acc1[0], 0.f); v.y = fmaxf(acc1[1], 0.f);
        v.z = fmaxf(acc1[2], 0.f); v.w = fmaxf(acc1[3], 0.f);
        *(float4*)&out[(((long)t * N + n0 + 1) << 7) + dq * 4] = v;
    }
}

__global__ __launch_bounds__(256) void gnn_dense16_adm(const float* __restrict__ m1,
        const float* __restrict__ m2,
        const float* __restrict__ hin, long hinStride,
        const float* __restrict__ gw, const float* __restrict__ gb,
        int l, float* __restrict__ out) {
    const int rpt = kNADM / 16;  // 128
    int t = blockIdx.x / rpt, rt = blockIdx.x % rpt;
    int r0 = rt * 16;
    int tid = threadIdx.x;
    int dq = tid & 31, rg = tid >> 5;
    __shared__ float R1[16][kD], R2[16][kD];
    for (int x = tid; x < 16 * kD; x += 256) {
        int r = x >> 7, dd = x & 127;
        long n = r0 + r;
        long o = (((long)t * kNADM + n) << 7) + dd;
        float h = hin[t * hinStride + (n << 7) + dd];
        R1[r][dd] = m1[o] + h;
        R2[r][dd] = m2[o] + h;
    }
    __syncthreads();
    long w1o = ((long)t * 2 + l) * 4 + 1, w3o = w1o + 2;
    const float* W1 = gw + (w1o << 14);
    const float* W3 = gw + (w3o << 14);
    float acc0[4], acc1[4];
#pragma unroll
    for (int j = 0; j < 4; ++j) {
        float bv = gb[(w1o << 7) + dq * 4 + j] + gb[(w3o << 7) + dq * 4 + j];
        acc0[j] = bv; acc1[j] = bv;
    }
    const float* P0 = &R1[rg * 2][0];
    const float* P1 = &R1[rg * 2 + 1][0];
    const float* Q0 = &R2[rg * 2][0];
    const float* Q1 = &R2[rg * 2 + 1][0];
#pragma unroll 2
    for (int k = 0; k < kD; ++k) {
        float4 wa = *(const float4*)&W1[(k << 7) + dq * 4];
        float4 wb = *(const float4*)&W3[(k << 7) + dq * 4];
        float p0 = P0[k], p1 = P1[k], q0 = Q0[k], q1 = Q1[k];
        acc0[0] += p0 * wa.x + q0 * wb.x; acc0[1] += p0 * wa.y + q0 * wb.y;
        acc0[2] += p0 * wa.z + q0 * wb.z; acc0[3] += p0 * wa.w + q0 * wb.w;
        acc1[0] += p1 * wa.x + q1 * wb.x; acc1[1] += p1 * wa.y + q1 * wb.y;
        acc1[2] += p1 * wa.z + q1 * wb.z; acc1[3] += p1 * wa.w + q1 * wb.w;
    }
    long n0 = r0 + rg * 2;
    {
        float4 v;
        v.x = fmaxf(acc0[0], 0.f); v.y = fmaxf(acc0[1], 0.f);
        v.z = fmaxf(acc0[2], 0.f); v.w = fmaxf(acc0[3], 0.f);
        *(float4*)&out[(((long)t * kNADM + n0) << 7) + dq * 4] = v;
    }
    {
        float4 v;
        v.x = fmaxf(acc1[0], 0.f); v.y = fmaxf(acc1[1], 0.f);
        v.z = fmaxf(acc1[2], 0.f); v.w = fmaxf(acc1[3], 0.f);
        *(float4*)&out[(((long)t * kNADM + n0 + 1) << 7) + dq * 4] = v;
    }
}

// ---------------- sinusoidal PE ----------------
__global__ void pe_kernel(float* __restrict__ x, int N) {
    int t = blockIdx.x / N, d = threadIdx.x;
    long o = (long)blockIdx.x * kD + d;
    float ang = (float)t * expf(-(float)(d & ~1) * (9.210340371976184f / 128.f));
    x[o] += (d & 1) ? cosf(ang) : sinf(ang);
}

__global__ void copy_kernel(float* __restrict__ dst, const float* __restrict__ src, long n) {
    long i = (long)blockIdx.x * blockDim.x + threadIdx.x;
    if (i < n) dst[i] = src[i];
}

// ---------------- weight pack: fp32 [slices][K][N] -> bf16 B-fragment order ----------------
__global__ void pack_w(const float* __restrict__ W, short* __restrict__ out,
                       int K, int N, long total) {
    long idx = (long)blockIdx.x * blockDim.x + threadIdx.x;
    if (idx >= total) return;
    long per = (long)K * N;
    long s = idx / per, r = idx % per;
    int k = (int)(r / N), n = (int)(r % N);
    int tile = n >> 4, kcg = k >> 5, quad = (k >> 3) & 3, j = k & 7;
    int lane = quad * 16 + (n & 15);
    long pidx = (((long)tile * (K >> 5) + kcg) * 64 + lane) * 8 + j;
    out[s * per + pidx] = (short)f2b(W[idx]);
}

// ---------------- batched (3-decoder) MFMA GEMM ----------------
struct B3 {
    const float* A[3]; const short* Bp[3]; const float* bias[3];
    float* C[3]; int M[3]; int bend[3];
};

template<int K, int N, bool RELU>
__global__ __launch_bounds__(256) void mfma_gemm_b(B3 p, int ldc) {
    constexpr int KS = (K > 128) ? 128 : K;    // staged K per round
    constexpr int KB = K / KS;                 // staging rounds
    constexpr int NT = N / 16;                 // col tiles
    constexpr int NA = (KB > 1) ? NT : 1;      // accumulator tiles held
    constexpr int PITCH = KS + 8;              // shorts per LDS row
    __shared__ short Alds[64 * PITCH];
    int bid = blockIdx.x;
    int di = (bid >= p.bend[0]) + (bid >= p.bend[1]);
    int bbase = di ? p.bend[di - 1] : 0;
    const float* A = p.A[di];
    const short* Bp = p.Bp[di];
    const float* bias = p.bias[di];
    float* C = p.C[di];
    int M = p.M[di];
    int m0 = (bid - bbase) * 64;
    int tid = threadIdx.x;
    int wave = tid >> 6, lane = tid & 63;
    int lrow = lane & 15, quad = lane >> 4;

    floatx4 acc[NA];
#pragma unroll
    for (int i = 0; i < NA; ++i) acc[i] = (floatx4){0.f, 0.f, 0.f, 0.f};

    for (int kb = 0; kb < KB; ++kb) {
        if (kb) __syncthreads();
        for (int i = tid; i < 64 * (KS / 2); i += 256) {
            int r = i / (KS / 2), kp = i % (KS / 2);
            int row = m0 + r;
            float2 v = make_float2(0.f, 0.f);
            if (row < M) v = *(const float2*)&A[(long)row * K + kb * KS + 2 * kp];
            unsigned u = (unsigned)f2b(v.x) | ((unsigned)f2b(v.y) << 16);
            *(unsigned*)&Alds[r * PITCH + 2 * kp] = u;
        }
        __syncthreads();

        for (int nt = 0; nt < NT; ++nt) {
            int ai = (KB > 1) ? nt : 0;
            if (KB == 1) acc[0] = (floatx4){0.f, 0.f, 0.f, 0.f};
#pragma unroll
            for (int kc = 0; kc < KS / 32; ++kc) {
                short8 a = *(const short8*)&Alds[(wave * 16 + lrow) * PITCH + kc * 32 + quad * 8];
                int kcg = kb * (KS / 32) + kc;
                short8 b = *(const short8*)(Bp + (((long)nt * (K / 32) + kcg) * 64 + lane) * 8);
                acc[ai] = __builtin_amdgcn_mfma_f32_16x16x32_bf16(a, b, acc[ai], 0, 0, 0);
            }
            if (KB == 1) {
                int col = nt * 16 + lrow;
                float bv = bias[col];
#pragma unroll
                for (int r = 0; r < 4; ++r) {
                    int row = m0 + wave * 16 + quad * 4 + r;
                    if (row < M) {
                        float v = acc[0][r] + bv;
                        if (RELU && v < 0.f) v = 0.f;
                        C[(long)row * ldc + col] = v;
                    }
                }
            }
        }
    }
    if (KB > 1) {
#pragma unroll
        for (int nt = 0; nt < NT; ++nt) {
            int col = nt * 16 + lrow;
            float bv = bias[col];
#pragma unroll
            for (int r = 0; r < 4; ++r) {
                int row = m0 + wave * 16 + quad * 4 + r;
                if (row < M) {
                    float v = acc[nt][r] + bv;
                    if (RELU && v < 0.f) v = 0.f;
                    C[(long)row * ldc + col] = v;
                }
            }
        }
    }
}

// ---------------- batched per-node causal attention T=8,H=8,HD=16 ----------------
struct A3 { const float* q[3]; float* o[3]; int N[3]; int end[3]; };

__global__ void attn_b(A3 p) {
    int idx = blockIdx.x * blockDim.x + threadIdx.x;
    if (idx >= p.end[2]) return;
    int i = (idx >= p.end[0]) + (idx >= p.end[1]);
    int base = i ? p.end[i - 1] : 0;
    int r0 = idx - base;
    int N = p.N[i];
    const float* qkv = p.q[i];
    float* o = p.o[i];
    int n = r0 >> 6;
    int rr = r0 & 63;
    int h = rr >> 3, s = rr & 7;
    const float* qp = qkv + ((long)s * N + n) * 384 + h * kHD;
    float q[kHD];
#pragma unroll
    for (int j = 0; j < kHD; ++j) q[j] = qp[j];
    float sc[kT];
    float mx = -1e30f;
    for (int m = 0; m <= s; ++m) {
        const float* kp = qkv + ((long)m * N + n) * 384 + 128 + h * kHD;
        float dacc = 0.f;
#pragma unroll
        for (int j = 0; j < kHD; ++j) dacc += q[j] * kp[j];
        dacc *= 0.25f;
        sc[m] = dacc;
        mx = fmaxf(mx, dacc);
    }
    float sum = 0.f;
    for (int m = 0; m <= s; ++m) { sc[m] = expf(sc[m] - mx); sum += sc[m]; }
    float inv = 1.f / sum;
    float ov[kHD];
#pragma unroll
    for (int j = 0; j < kHD; ++j) ov[j] = 0.f;
    for (int m = 0; m <= s; ++m) {
        const float* vp = qkv + ((long)m * N + n) * 384 + 256 + h * kHD;
        float am = sc[m] * inv;
#pragma unroll
        for (int j = 0; j < kHD; ++j) ov[j] += am * vp[j];
    }
    float* op = o + ((long)s * N + n) * kD + h * kHD;
#pragma unroll
    for (int j = 0; j < kHD; ++j) op[j] = ov[j];
}

// ---------------- batched x = LN(x + y) * g + b, one wave per row ----------------
struct L3 { float* X[3]; const float* Y[3]; const float* g[3]; const float* b[3]; int rend[3]; };

__global__ __launch_bounds__(256) void res_ln_b(L3 p) {
    int row = blockIdx.x * 4 + (threadIdx.x >> 6);
    if (row >= p.rend[2]) return;
    int lane = threadIdx.x & 63;
    int i = (row >= p.rend[0]) + (row >= p.rend[1]);
    int rbase = i ? p.rend[i - 1] : 0;
    long o = ((long)(row - rbase)) << 7;
    float* X = p.X[i];
    const float* Y = p.Y[i];
    float v0 = X[o + lane] + Y[o + lane];
    float v1 = X[o + 64 + lane] + Y[o + 64 + lane];
    float s = v0 + v1;
#pragma unroll
    for (int st = 32; st > 0; st >>= 1) s += __shfl_xor(s, st);
    float mu = s * (1.f / 128.f);
    float d0 = v0 - mu, d1 = v1 - mu;
    float vv = d0 * d0 + d1 * d1;
#pragma unroll
    for (int st = 32; st > 0; st >>= 1) vv += __shfl_xor(vv, st);
    float inv = rsqrtf(vv * (1.f / 128.f) + 1e-5f);
    X[o + lane] = d0 * inv * p.g[i][lane] + p.b[i][lane];
    X[o + 64 + lane] = d1 * inv * p.g[i][lane + 64] + p.b[i][lane + 64];
}

// ---------------- scores: fp32 64x64 tile, 4x4 per thread, transposed LDS ----------------
__global__ __launch_bounds__(256) void score_kernel(const float* __restrict__ A, const float* __restrict__ B,
                                                    float* __restrict__ out, int M, int Nn) {
    int t = blockIdx.z;
    const float* At = A + (long)t * M * kD;
    const float* Bt = B + (long)t * Nn * kD;
    float* Ot = out + (long)t * M * Nn;
    int bm = blockIdx.y * 64, bn = blockIdx.x * 64;
    int tid = threadIdx.x;
    int cx = tid & 15, ry = tid >> 4;
    __shared__ float As[32 * 68];
    __shared__ float Bs[32 * 68];
    float acc[4][4];
#pragma unroll
    for (int i = 0; i < 4; ++i)
#pragma unroll
        for (int j = 0; j < 4; ++j) acc[i][j] = 0.f;

    for (int k0 = 0; k0 < kD; k0 += 32) {
        __syncthreads();
        for (int i = tid; i < 64 * 32; i += 256) {
            int r = i >> 5, c = i & 31;
            int am = bm + r;
            As[c * 68 + r] = (am < M) ? At[(long)am * kD + k0 + c] : 0.f;
            int bnn = bn + r;
            Bs[c * 68 + r] = (bnn < Nn) ? Bt[(long)bnn * kD + k0 + c] : 0.f;
        }
        __syncthreads();
#pragma unroll 4
        for (int k = 0; k < 32; ++k) {
            float4 a = *(const float4*)&As[k * 68 + ry * 4];
            float4 b = *(const float4*)&Bs[k * 68 + cx * 4];
            float av[4] = {a.x, a.y, a.z, a.w};
            float bv[4] = {b.x, b.y, b.z, b.w};
#pragma unroll
            for (int i = 0; i < 4; ++i)
#pragma unroll
                for (int j = 0; j < 4; ++j) acc[i][j] += av[i] * bv[j];
        }
    }
#pragma unroll
    for (int i = 0; i < 4; ++i) {
        int om = bm + ry * 4 + i;
        if (om >= M) continue;
#pragma unroll
        for (int j = 0; j < 4; ++j) {
            int on = bn + cx * 4 + j;
            if (on < Nn) Ot[(long)om * Nn + on] = acc[i][j];
        }
    }
}

// ---------------- labels scatter ----------------
__global__ void label_kernel(const int* __restrict__ s_, const int* __restrict__ d_,
                             float* __restrict__ out, int Nn) {
    int idx = blockIdx.x * blockDim.x + threadIdx.x;
    if (idx >= kT * kE) return;
    int t = idx >> 14;
    int s = s_[idx], dd = d_[idx];
    out[(long)t * kNADM * Nn + (long)s * Nn + dd] = 1.0f;
}

extern "C" void kernel_launch(void* const* d_in, const int* in_sizes, int n_in,
                              void* d_out, int out_size, void* d_ws, size_t ws_size,
                              hipStream_t stream) {
    const float* x_adm       = (const float*)d_in[0];
    const float* x_lab       = (const float*)d_in[1];
    const float* x_drug      = (const float*)d_in[2];
    const float* edge_x_did  = (const float*)d_in[3];
    const float* edge_x_took = (const float*)d_in[4];
    const float* w_proj_adm  = (const float*)d_in[5];
    const float* b_proj_adm  = (const float*)d_in[6];
    const float* w_proj_lab  = (const float*)d_in[7];
    const float* b_proj_lab  = (const float*)d_in[8];
    const float* w_proj_drug = (const float*)d_in[9];
    const float* b_proj_drug = (const float*)d_in[10];
    const float* w_proj_e    = (const float*)d_in[11];
    const float* b_proj_e    = (const float*)d_in[12];
    const float* w_proj_e4d  = (const float*)d_in[13];
    const float* b_proj_e4d  = (const float*)d_in[14];
    const float* emb_lab     = (const float*)d_in[15];
    const float* emb_drug    = (const float*)d_in[16];
    const float* gnn_w       = (const float*)d_in[17];
    const float* gnn_b       = (const float*)d_in[18];
    const float* dec_sa_in_w  = (const float*)d_in[19];
    const float* dec_sa_in_b  = (const float*)d_in[20];
    const float* dec_sa_out_w = (const float*)d_in[21];
    const float* dec_sa_out_b = (const float*)d_in[22];
    const float* dec_ca_in_w  = (const float*)d_in[23];
    const float* dec_ca_in_b  = (const float*)d_in[24];
    const float* dec_ca_out_w = (const float*)d_in[25];
    const float* dec_ca_out_b = (const float*)d_in[26];
    const float* dec_ff1_w    = (const float*)d_in[27];
    const float* dec_ff1_b    = (const float*)d_in[28];
    const float* dec_ff2_w    = (const float*)d_in[29];
    const float* dec_ff2_b    = (const float*)d_in[30];
    const float* dec_ln1_w    = (const float*)d_in[31];
    const float* dec_ln1_b    = (const float*)d_in[32];
    const float* dec_ln2_w    = (const float*)d_in[33];
    const float* dec_ln2_b    = (const float*)d_in[34];
    const float* dec_ln3_w    = (const float*)d_in[35];
    const float* dec_ln3_b    = (const float*)d_in[36];
    const int* node_id_lab  = (const int*)d_in[37];
    const int* node_id_drug = (const int*)d_in[38];
    const int* src_did      = (const int*)d_in[39];
    const int* dst_did      = (const int*)d_in[40];
    const int* src_took     = (const int*)d_in[41];
    const int* dst_took     = (const int*)d_in[42];
    const int* lbl_src_did  = (const int*)d_in[43];
    const int* lbl_dst_did  = (const int*)d_in[44];
    const int* lbl_src_took = (const int*)d_in[45];
    const int* lbl_dst_took = (const int*)d_in[46];

    float* out_f = (float*)d_out;
    const long SC1 = (long)kT * kNADM * kNLAB;    // 12,337,152
    const long SC2 = (long)kT * kNADM * kNDRUG;   // 70,352,896
    float* out_scores  = out_f;
    float* out_labels  = out_f + SC1;
    float* out_scores4 = out_f + 2 * SC1;
    float* out_labels4 = out_f + 2 * SC1 + SC2;

    // scratch arena inside d_out (scores4 + labels4 regions; both dead until the end)
    float* SCR = out_scores4;                     // 70.3M floats
    float* Sp  = out_labels4;
    const long SA_SZ = (long)kT * kNADM * kD;     // 2,097,152
    const long SL_SZ = (long)kT * kNLAB * kD;     //   771,072
    const long SD_SZ = (long)kT * kNDRUG * kD;    // 4,397,056
    float* Sa = Sp;
    float* Sl = Sa + SA_SZ;
    float* Sd = Sl + SL_SZ;                       // ends 7,265,280 (contiguous Sa|Sl|Sd)
    short* pk_base = (short*)(Sp + 7265288);
    const long PS_SA_IN = 18L * 128 * 384;
    const long PS_SA_OUT = 18L * 128 * 128;
    const long PS_CA_IN = PS_SA_IN;
    const long PS_CA_OUT = PS_SA_OUT;
    const long PS_FF1 = 18L * 128 * 512;
    const long PS_FF2 = 18L * 512 * 128;
    short* pk_sa_in  = pk_base;
    short* pk_sa_out = pk_sa_in + PS_SA_IN;
    short* pk_ca_in  = pk_sa_out + PS_SA_OUT;
    short* pk_ca_out = pk_ca_in + PS_CA_IN;
    short* pk_ff1    = pk_ca_out + PS_CA_OUT;
    short* pk_ff2    = pk_ff1 + PS_FF1;

    // GNN-phase aliases in SCR
    float* h0a = SCR;
    float* h0l = h0a + (long)kNADM * kD;
    float* h0d = h0l + (long)kNLAB * kD;
    float* Ta  = h0d + (long)kNDRUG * kD;
    float* Tl  = Ta + SA_SZ;
    float* Td  = Tl + SL_SZ;
    float* msgA1 = Td + SD_SZ;
    float* msgA2 = msgA1 + SA_SZ;
    float* msgL  = msgA2 + SA_SZ;
    float* msgD  = msgL + SL_SZ;
    const long MSG_SZ = SA_SZ * 2 + SL_SZ + SD_SZ;

    // decoder-phase aliases in SCR: per-decoder disjoint bigbuf/obuf/membuf
    const int TNs[3] = {kT * kNADM, kT * kNLAB, kT * kNDRUG};   // 16384, 6024, 34352
    const int Ns_[3] = {kNADM, kNLAB, kNDRUG};
    const long rowsTot = (long)TNs[0] + TNs[1] + TNs[2];        // 56760
    const long roff[3] = {0, (long)TNs[0], (long)TNs[0] + TNs[1]};
    float* obase = SCR + rowsTot * 512;                         // bigbuf = SCR.. (29.06M)
    float* mbase = obase + rowsTot * 128;                       // obuf (7.27M) | membuf (7.27M); total 43.6M < 70.3M
    float* Xs[3] = {Sa, Sl, Sd};
    float* bb[3]; float* ob[3]; float* mb[3];
    for (int i = 0; i < 3; ++i) {
        bb[i] = SCR + roff[i] * 512;
        ob[i] = obase + roff[i] * 128;
        mb[i] = mbase + roff[i] * 128;
    }
    const int gB[3] = {(TNs[0] + 63) / 64, (TNs[1] + 63) / 64, (TNs[2] + 63) / 64}; // 256,95,537
    const int bend[3] = {gB[0], gB[0] + gB[1], gB[0] + gB[1] + gB[2]};              // 256,351,888
    const int gTot = bend[2];
    const int aend[3] = {TNs[0] * 8, (TNs[0] + TNs[1]) * 8, (int)rowsTot * 8};      // N*H*T prefix
    const int rend[3] = {TNs[0], TNs[0] + TNs[1], (int)rowsTot};
    const int aBlocks = (aend[2] + 255) / 256;
    const int lnBlocks = (rend[2] + 3) / 4;

    // ---- pack decoder weights to bf16 fragment order ----
    {
        long t1 = PS_SA_IN;
        pack_w<<<(int)((t1 + 255) / 256), 256, 0, stream>>>(dec_sa_in_w, pk_sa_in, 128, 384, t1);
        long t2 = PS_SA_OUT;
        pack_w<<<(int)((t2 + 255) / 256), 256, 0, stream>>>(dec_sa_out_w, pk_sa_out, 128, 128, t2);
        pack_w<<<(int)((t1 + 255) / 256), 256, 0, stream>>>(dec_ca_in_w, pk_ca_in, 128, 384, t1);
        pack_w<<<(int)((t2 + 255) / 256), 256, 0, stream>>>(dec_ca_out_w, pk_ca_out, 128, 128, t2);
        long t3 = PS_FF1;
        pack_w<<<(int)((t3 + 255) / 256), 256, 0, stream>>>(dec_ff1_w, pk_ff1, 128, 512, t3);
        pack_w<<<(int)((t3 + 255) / 256), 256, 0, stream>>>(dec_ff2_w, pk_ff2, 512, 128, t3);
    }

    // ---- node projections ----
    proj_kernel<<<kNADM,  kD, 0, stream>>>(x_adm,  8, w_proj_adm,  b_proj_adm,  nullptr,  nullptr,      h0a);
    proj_kernel<<<kNLAB,  kD, 0, stream>>>(x_lab,  2, w_proj_lab,  b_proj_lab,  emb_lab,  node_id_lab,  h0l);
    proj_kernel<<<kNDRUG, kD, 0, stream>>>(x_drug, 8, w_proj_drug, b_proj_drug, emb_drug, node_id_drug, h0d);

    // ---- GNN: 2 layers ----
    for (int l = 0; l < 2; ++l) {
        hipMemsetAsync((void*)msgA1, 0, (size_t)MSG_SZ * sizeof(float), stream);
        const float *ha, *hl, *hd;
        long sa, sl, sd;
        float *oa, *ol, *od;
        if (l == 0) { ha = h0a; hl = h0l; hd = h0d; sa = sl = sd = 0;
                      oa = Ta; ol = Tl; od = Td; }
        else        { ha = Ta; hl = Tl; hd = Td;
                      sa = (long)kNADM * kD; sl = (long)kNLAB * kD; sd = (long)kNDRUG * kD;
                      oa = Sa; ol = Sl; od = Sd; }
        msg_kernel<<<kT * kE, kD, 0, stream>>>(edge_x_did, 2, src_did, dst_did, w_proj_e, b_proj_e,
                                               ha, sa, hl, sl, msgL, kNLAB, msgA1, kNADM);
        msg_kernel<<<kT * kE, kD, 0, stream>>>(edge_x_took, 7, src_took, dst_took, w_proj_e4d, b_proj_e4d,
                                               ha, sa, hd, sd, msgD, kNDRUG, msgA2, kNADM);
        gnn_dense16_adm<<<kT * (kNADM / 16), 256, 0, stream>>>(msgA1, msgA2, ha, sa, gnn_w, gnn_b, l, oa);
        gnn_dense16<<<kT * 48,  256, 0, stream>>>(msgL, hl, sl, gnn_w, gnn_b, l, 0, ol, kNLAB, 48);
        gnn_dense16<<<kT * 269, 256, 0, stream>>>(msgD, hd, sd, gnn_w, gnn_b, l, 2, od, kNDRUG, 269);
    }

    // ---- positional encoding ----
    pe_kernel<<<kT * kNADM,  kD, 0, stream>>>(Sa, kNADM);
    pe_kernel<<<kT * kNLAB,  kD, 0, stream>>>(Sl, kNLAB);
    pe_kernel<<<kT * kNDRUG, kD, 0, stream>>>(Sd, kNDRUG);

    // ---- decoders: all 3 batched per launch ----
    // memory = decoder input; Sa|Sl|Sd contiguous -> single copy
    copy_kernel<<<(int)((rowsTot * 128 + 255) / 256), 256, 0, stream>>>(mbase, Sa, rowsTot * 128);

    for (int l = 0; l < kL; ++l) {
        long wi[3] = {(long)l, (long)(kL + l), (long)(2 * kL + l)};
        B3 g; A3 at; L3 ln;
        for (int i = 0; i < 3; ++i) {
            g.M[i] = TNs[i]; g.bend[i] = bend[i];
            at.N[i] = Ns_[i]; at.end[i] = aend[i];
            ln.rend[i] = rend[i];
            at.o[i] = ob[i];
            ln.X[i] = Xs[i];
        }
        // self-attention qkv
        for (int i = 0; i < 3; ++i) {
            g.A[i] = Xs[i]; g.Bp[i] = pk_sa_in + wi[i] * 49152;
            g.bias[i] = dec_sa_in_b + wi[i] * 384; g.C[i] = bb[i];
        }
        mfma_gemm_b<128, 384, false><<<gTot, 256, 0, stream>>>(g, 384);
        for (int i = 0; i < 3; ++i) at.q[i] = bb[i];
        attn_b<<<aBlocks, 256, 0, stream>>>(at);
        for (int i = 0; i < 3; ++i) {
            g.A[i] = ob[i]; g.Bp[i] = pk_sa_out + wi[i] * 16384;
            g.bias[i] = dec_sa_out_b + wi[i] * kD; g.C[i] = bb[i];
        }
        mfma_gemm_b<128, 128, false><<<gTot, 256, 0, stream>>>(g, kD);
        for (int i = 0; i < 3; ++i) {
            ln.Y[i] = bb[i];
            ln.g[i] = dec_ln1_w + wi[i] * kD; ln.b[i] = dec_ln1_b + wi[i] * kD;
        }
        res_ln_b<<<lnBlocks, 256, 0, stream>>>(ln);
        // cross-attention: q from X, kv from memory
        for (int i = 0; i < 3; ++i) {
            g.A[i] = Xs[i]; g.Bp[i] = pk_ca_in + wi[i] * 49152;
            g.bias[i] = dec_ca_in_b + wi[i] * 384; g.C[i] = bb[i];
        }
        mfma_gemm_b<128, 128, false><<<gTot, 256, 0, stream>>>(g, 384);
        for (int i = 0; i < 3; ++i) {
            g.A[i] = mb[i]; g.Bp[i] = pk_ca_in + wi[i] * 49152 + 16384;
            g.bias[i] = dec_ca_in_b + wi[i] * 384 + 128; g.C[i] = bb[i] + 128;
        }
        mfma_gemm_b<128, 256, false><<<gTot, 256, 0, stream>>>(g, 384);
        attn_b<<<aBlocks, 256, 0, stream>>>(at);
        for (int i = 0; i < 3; ++i) {
            g.A[i] = ob[i]; g.Bp[i] = pk_ca_out + wi[i] * 16384;
            g.bias[i] = dec_ca_out_b + wi[i] * kD; g.C[i] = bb[i];
        }
        mfma_gemm_b<128, 128, false><<<gTot, 256, 0, stream>>>(g, kD);
        for (int i = 0; i < 3; ++i) {
            ln.Y[i] = bb[i];
            ln.g[i] = dec_ln2_w + wi[i] * kD; ln.b[i] = dec_ln2_b + wi[i] * kD;
        }
        res_ln_b<<<lnBlocks, 256, 0, stream>>>(ln);
        // feed-forward
        for (int i = 0; i < 3; ++i) {
            g.A[i] = Xs[i]; g.Bp[i] = pk_ff1 + wi[i] * 65536;
            g.bias[i] = dec_ff1_b + wi[i] * kFF; g.C[i] = bb[i];
        }
        mfma_gemm_b<128, 512, true><<<gTot, 256, 0, stream>>>(g, kFF);
        for (int i = 0; i < 3; ++i) {
            g.A[i] = bb[i]; g.Bp[i] = pk_ff2 + wi[i] * 65536;
            g.bias[i] = dec_ff2_b + wi[i] * kD; g.C[i] = ob[i];
        }
        mfma_gemm_b<512, 128, false><<<gTot, 256, 0, stream>>>(g, kD);
        for (int i = 0; i < 3; ++i) {
            ln.Y[i] = ob[i];
            ln.g[i] = dec_ln3_w + wi[i] * kD; ln.b[i] = dec_ln3_b + wi[i] * kD;
        }
        res_ln_b<<<lnBlocks, 256, 0, stream>>>(ln);
    }

    // scores (adm x lab)
    score_kernel<<<dim3((kNLAB + 63) / 64, kNADM / 64, kT), 256, 0, stream>>>(Sa, Sl, out_scores, kNADM, kNLAB);
    // labels (did)
    hipMemsetAsync((void*)out_labels, 0, (size_t)SC1 * sizeof(float), stream);
    label_kernel<<<(kT * kE + 255) / 256, 256, 0, stream>>>(lbl_src_did, lbl_dst_did, out_labels, kNLAB);
    // scores4 (adm x drug): writes over SCR (dead), reads Sa/Sd — disjoint
    score_kernel<<<dim3((kNDRUG + 63) / 64, kNADM / 64, kT), 256, 0, stream>>>(Sa, Sd, out_scores4, kNADM, kNDRUG);
    // labels4 LAST (memset clobbers Sa/Sl/Sd + packed weights, all dead now)
    hipMemsetAsync((void*)out_labels4, 0, (size_t)SC2 * sizeof(float), stream);
    label_kernel<<<(kT * kE + 255) / 256, 256, 0, stream>>>(lbl_src_took, lbl_dst_took, out_labels4, kNDRUG);

    (void)in_sizes; (void)n_in; (void)out_size; (void)d_ws; (void)ws_size;
}

// Round 2
// 3193.401 us; speedup vs baseline: 2.0208x; 1.2214x over previous
//
#include <hip/hip_runtime.h>
#include <hip/hip_bf16.h>

// problem constants
#define kT 8
#define kD 128
#define kH 8
#define kHD 16
#define kFF 512
#define kL 6
#define kNADM 2048
#define kNLAB 753
#define kNDRUG 4294
#define kE 16384

typedef __attribute__((ext_vector_type(8))) short short8;
typedef __attribute__((ext_vector_type(4))) float floatx4;

// round-to-nearest-even fp32 -> bf16 bits
__device__ __forceinline__ unsigned short f2b(float f) {
    unsigned x = __float_as_uint(f);
    unsigned r = (x + 0x7fffu + ((x >> 16) & 1u)) >> 16;
    return (unsigned short)r;
}

__device__ __forceinline__ float quad_reduce16(float v) {
    v += __shfl_xor(v, 1);
    v += __shfl_xor(v, 2);
    v += __shfl_xor(v, 4);
    v += __shfl_xor(v, 8);
    return v;
}

// ---------------- merged weight pack: fp32 [slices][K][N] -> bf16 B-fragment order ----------------
struct PK6 { const float* W[6]; short* out[6]; int K[6]; int N[6]; long tot[6]; int bend[6]; };

__global__ void pack6(PK6 p) {
    int bid = blockIdx.x;
    int di = 0;
    while (bid >= p.bend[di]) ++di;
    int bstart = di ? p.bend[di - 1] : 0;
    long idx = (long)(bid - bstart) * 256 + threadIdx.x;
    if (idx >= p.tot[di]) return;
    int K = p.K[di], N = p.N[di];
    long per = (long)K * N;
    long s = idx / per, r = idx % per;
    int k = (int)(r / N), n = (int)(r % N);
    int tile = n >> 4, kcg = k >> 5, quad = (k >> 3) & 3, j = k & 7;
    int lane = quad * 16 + (n & 15);
    long pidx = (((long)tile * (K >> 5) + kcg) * 64 + lane) * 8 + j;
    p.out[di][s * per + pidx] = (short)f2b(p.W[di][idx]);
}

// ---------------- merged node projections ----------------
__global__ void proj3(const float* __restrict__ xa, const float* __restrict__ wa, const float* __restrict__ ba,
                      const float* __restrict__ xl, const float* __restrict__ wl, const float* __restrict__ bl,
                      const float* __restrict__ el, const int* __restrict__ nl,
                      const float* __restrict__ xd, const float* __restrict__ wd, const float* __restrict__ bd,
                      const float* __restrict__ ed, const int* __restrict__ nd,
                      float* __restrict__ oa, float* __restrict__ ol, float* __restrict__ od) {
    int bid = blockIdx.x, d = threadIdx.x;
    const float* x; const float* w; const float* b; const float* emb = nullptr;
    const int* nid = nullptr; float* out; int IK, n;
    if (bid < kNADM) { n = bid; x = xa; w = wa; b = ba; out = oa; IK = 8; }
    else if (bid < kNADM + kNLAB) { n = bid - kNADM; x = xl; w = wl; b = bl; emb = el; nid = nl; out = ol; IK = 2; }
    else { n = bid - kNADM - kNLAB; x = xd; w = wd; b = bd; emb = ed; nid = nd; out = od; IK = 8; }
    float acc = b[d];
    for (int k = 0; k < IK; ++k) acc += x[(long)n * IK + k] * w[k * kD + d];
    if (emb) acc += emb[(long)nid[n] * kD + d];
    out[(long)n * kD + d] = acc;
}

// ---------------- GINE messages, both edge types in one launch ----------------
struct M2 {
    const float* ex[2]; int ek[2];
    const int* src[2]; const int* dst[2];
    const float* we[2]; const float* be[2];
    const float* hS[2]; long hSs[2];
    const float* hD[2]; long hDs[2];
    float* msgDst[2]; int Ndst[2];
    float* msgSrc[2]; int Nsrc[2];
};

__global__ void msg2(M2 p) {
    int g = blockIdx.x;
    int u = g >> 17;              // edge type
    int idx = g & (kT * kE - 1);
    int t = idx >> 14;
    int d = threadIdx.x;
    int s = p.src[u][idx], dd = p.dst[u][idx];
    int ek = p.ek[u];
    const float* exp_ = p.ex[u] + (long)idx * ek;
    const float* we = p.we[u];
    float e = p.be[u][d];
    for (int k = 0; k < ek; ++k) e += exp_[k] * we[k * kD + d];
    float vf = p.hS[u][t * p.hSs[u] + (long)s * kD + d] + e; if (vf < 0.f) vf = 0.f;
    atomicAdd(&p.msgDst[u][((long)t * p.Ndst[u] + dd) * kD + d], vf);
    float vr = p.hD[u][t * p.hDs[u] + (long)dd * kD + d] + e; if (vr < 0.f) vr = 0.f;
    atomicAdd(&p.msgSrc[u][((long)t * p.Nsrc[u] + s) * kD + d], vr);
}

// ---------------- merged GNN dense: adm + lab + drug in one launch ----------------
struct GD {
    const float* m1; const float* m2; const float* mL; const float* mD;
    const float* ha; const float* hl; const float* hd;
    long sa, sl, sd;
    const float* gw; const float* gb; int l;
    float* oa; float* ol; float* od;
};

__global__ __launch_bounds__(256) void gdense(GD p) {
    int bid = blockIdx.x;
    int tid = threadIdx.x;
    int dq = tid & 31, rg = tid >> 5;
    __shared__ float R1[16][kD], R2[16][kD];
    if (bid < 1024) {
        // ---- adm path: two messages, two weight mats ----
        int t = bid >> 7, rt = bid & 127;
        int r0 = rt * 16;
        for (int x = tid; x < 16 * kD; x += 256) {
            int r = x >> 7, dd2 = x & 127;
            long n = r0 + r;
            long o = (((long)t * kNADM + n) << 7) + dd2;
            float h = p.ha[t * p.sa + (n << 7) + dd2];
            R1[r][dd2] = p.m1[o] + h;
            R2[r][dd2] = p.m2[o] + h;
        }
        __syncthreads();
        long w1o = ((long)t * 2 + p.l) * 4 + 1, w3o = w1o + 2;
        const float* W1 = p.gw + (w1o << 14);
        const float* W3 = p.gw + (w3o << 14);
        float acc0[4], acc1[4];
#pragma unroll
        for (int j = 0; j < 4; ++j) {
            float bv = p.gb[(w1o << 7) + dq * 4 + j] + p.gb[(w3o << 7) + dq * 4 + j];
            acc0[j] = bv; acc1[j] = bv;
        }
        const float* P0 = &R1[rg * 2][0];
        const float* P1 = &R1[rg * 2 + 1][0];
        const float* Q0 = &R2[rg * 2][0];
        const float* Q1 = &R2[rg * 2 + 1][0];
#pragma unroll 2
        for (int k = 0; k < kD; ++k) {
            float4 wa4 = *(const float4*)&W1[(k << 7) + dq * 4];
            float4 wb4 = *(const float4*)&W3[(k << 7) + dq * 4];
            float p0 = P0[k], p1 = P1[k], q0 = Q0[k], q1 = Q1[k];
            acc0[0] += p0 * wa4.x + q0 * wb4.x; acc0[1] += p0 * wa4.y + q0 * wb4.y;
            acc0[2] += p0 * wa4.z + q0 * wb4.z; acc0[3] += p0 * wa4.w + q0 * wb4.w;
            acc1[0] += p1 * wa4.x + q1 * wb4.x; acc1[1] += p1 * wa4.y + q1 * wb4.y;
            acc1[2] += p1 * wa4.z + q1 * wb4.z; acc1[3] += p1 * wa4.w + q1 * wb4.w;
        }
        long n0 = r0 + rg * 2;
        float4 v;
        v.x = fmaxf(acc0[0], 0.f); v.y = fmaxf(acc0[1], 0.f);
        v.z = fmaxf(acc0[2], 0.f); v.w = fmaxf(acc0[3], 0.f);
        *(float4*)&p.oa[(((long)t * kNADM + n0) << 7) + dq * 4] = v;
        v.x = fmaxf(acc1[0], 0.f); v.y = fmaxf(acc1[1], 0.f);
        v.z = fmaxf(acc1[2], 0.f); v.w = fmaxf(acc1[3], 0.f);
        *(float4*)&p.oa[(((long)t * kNADM + n0 + 1) << 7) + dq * 4] = v;
    } else {
        // ---- generic path (lab / drug) ----
        const float* msg; const float* hin; long hs; float* out; int N, type, t, rt;
        if (bid < 1408) { int b = bid - 1024; t = b / 48; rt = b % 48; msg = p.mL; hin = p.hl; hs = p.sl; out = p.ol; N = kNLAB; type = 0; }
        else            { int b = bid - 1408; t = b / 269; rt = b % 269; msg = p.mD; hin = p.hd; hs = p.sd; out = p.od; N = kNDRUG; type = 2; }
        int r0 = rt * 16;
        for (int x = tid; x < 16 * kD; x += 256) {
            int r = x >> 7, dd2 = x & 127;
            int n = r0 + r;
            R1[r][dd2] = (n < N)
                ? msg[(((long)t * N + n) << 7) + dd2] + hin[t * hs + ((long)n << 7) + dd2]
                : 0.f;
        }
        __syncthreads();
        long wo = ((long)t * 2 + p.l) * 4 + type;
        const float* W = p.gw + (wo << 14);
        const float* bp = p.gb + (wo << 7) + dq * 4;
        float acc0[4], acc1[4];
#pragma unroll
        for (int j = 0; j < 4; ++j) { acc0[j] = bp[j]; acc1[j] = bp[j]; }
        const float* Rp0 = &R1[rg * 2][0];
        const float* Rp1 = &R1[rg * 2 + 1][0];
#pragma unroll 4
        for (int k = 0; k < kD; ++k) {
            float4 w4 = *(const float4*)&W[(k << 7) + dq * 4];
            float a0 = Rp0[k], a1 = Rp1[k];
            acc0[0] += a0 * w4.x; acc0[1] += a0 * w4.y; acc0[2] += a0 * w4.z; acc0[3] += a0 * w4.w;
            acc1[0] += a1 * w4.x; acc1[1] += a1 * w4.y; acc1[2] += a1 * w4.z; acc1[3] += a1 * w4.w;
        }
        int n0 = r0 + rg * 2;
        if (n0 < N) {
            float4 v;
            v.x = fmaxf(acc0[0], 0.f); v.y = fmaxf(acc0[1], 0.f);
            v.z = fmaxf(acc0[2], 0.f); v.w = fmaxf(acc0[3], 0.f);
            *(float4*)&out[(((long)t * N + n0) << 7) + dq * 4] = v;
        }
        if (n0 + 1 < N) {
            float4 v;
            v.x = fmaxf(acc1[0], 0.f); v.y = fmaxf(acc1[1], 0.f);
            v.z = fmaxf(acc1[2], 0.f); v.w = fmaxf(acc1[3], 0.f);
            *(float4*)&out[(((long)t * N + n0 + 1) << 7) + dq * 4] = v;
        }
    }
}

// ---------------- merged sinusoidal PE over contiguous Sa|Sl|Sd ----------------
__global__ void pe_all(float* __restrict__ X, int rend0, int rend1, int N0, int N1, int N2) {
    int r = blockIdx.x, d = threadIdx.x;
    int local, N;
    if (r < rend0)      { local = r;         N = N0; }
    else if (r < rend1) { local = r - rend0; N = N1; }
    else                { local = r - rend1; N = N2; }
    int t = local / N;
    float ang = (float)t * expf(-(float)(d & ~1) * (9.210340371976184f / 128.f));
    X[(long)r * kD + d] += (d & 1) ? cosf(ang) : sinf(ang);
}

__global__ void copy4(float4* __restrict__ dst, const float4* __restrict__ src, long n4) {
    long i = (long)blockIdx.x * blockDim.x + threadIdx.x;
    if (i < n4) dst[i] = src[i];
}

// ---------------- batched runtime-NT MFMA GEMM (K=128), up to 6 segments ----------------
struct G6 {
    const float* A[6]; const short* Bp[6]; const float* bias[6];
    float* C[6]; int M[6]; int bend[6]; int NT[6]; int ldc[6];
};

__global__ __launch_bounds__(256) void gemm_rtN(G6 p) {
    constexpr int PITCH = 136;
    __shared__ short Alds[64 * PITCH];
    int bid = blockIdx.x;
    int di = 0;
    while (bid >= p.bend[di]) ++di;
    int bbase = di ? p.bend[di - 1] : 0;
    const float* A = p.A[di];
    const short* Bp = p.Bp[di];
    const float* bias = p.bias[di];
    float* C = p.C[di];
    int M = p.M[di], NT = p.NT[di], ldc = p.ldc[di];
    int m0 = (bid - bbase) * 64;
    int tid = threadIdx.x;
    int wave = tid >> 6, lane = tid & 63;
    int lrow = lane & 15, quad = lane >> 4;

    for (int i = tid; i < 64 * 64; i += 256) {
        int r = i >> 6, kp = i & 63;
        int row = m0 + r;
        float2 v = make_float2(0.f, 0.f);
        if (row < M) v = *(const float2*)&A[(long)row * 128 + 2 * kp];
        *(unsigned*)&Alds[r * PITCH + 2 * kp] = (unsigned)f2b(v.x) | ((unsigned)f2b(v.y) << 16);
    }
    __syncthreads();
    short8 a[4];
#pragma unroll
    for (int kc = 0; kc < 4; ++kc)
        a[kc] = *(const short8*)&Alds[(wave * 16 + lrow) * PITCH + kc * 32 + quad * 8];

    for (int nt = 0; nt < NT; ++nt) {
        floatx4 acc = (floatx4){0.f, 0.f, 0.f, 0.f};
#pragma unroll
        for (int kc = 0; kc < 4; ++kc) {
            short8 b = *(const short8*)(Bp + (((long)nt * 4 + kc) * 64 + lane) * 8);
            acc = __builtin_amdgcn_mfma_f32_16x16x32_bf16(a[kc], b, acc, 0, 0, 0);
        }
        int col = nt * 16 + lrow;
        float bv = bias[col];
#pragma unroll
        for (int r = 0; r < 4; ++r) {
            int row = m0 + wave * 16 + quad * 4 + r;
            if (row < M) C[(long)row * ldc + col] = acc[r] + bv;
        }
    }
}

// ---------------- LN epilogue shared by gemm_ln / gemm_ff ----------------
__device__ __forceinline__ void ln_epilogue(floatx4* acc, const float* __restrict__ bias,
        float* __restrict__ X, const float* __restrict__ g, const float* __restrict__ b,
        int m0, int M, int wave, int lane) {
    int lrow = lane & 15, quad = lane >> 4;
    float gv[8], bv[8], biv[8];
#pragma unroll
    for (int nt = 0; nt < 8; ++nt) {
        int col = nt * 16 + lrow;
        gv[nt] = g[col]; bv[nt] = b[col]; biv[nt] = bias[col];
    }
#pragma unroll
    for (int r = 0; r < 4; ++r) {
        int row = m0 + wave * 16 + quad * 4 + r;
        if (row >= M) continue;                 // uniform per 16-lane quad
        long ro = (long)row * 128;
        float v[8]; float s = 0.f;
#pragma unroll
        for (int nt = 0; nt < 8; ++nt) {
            v[nt] = acc[nt][r] + biv[nt] + X[ro + nt * 16 + lrow];
            s += v[nt];
        }
        s = quad_reduce16(s);
        float mu = s * (1.f / 128.f);
        float vs = 0.f;
#pragma unroll
        for (int nt = 0; nt < 8; ++nt) { v[nt] -= mu; vs += v[nt] * v[nt]; }
        vs = quad_reduce16(vs);
        float inv = rsqrtf(vs * (1.f / 128.f) + 1e-5f);
#pragma unroll
        for (int nt = 0; nt < 8; ++nt)
            X[ro + nt * 16 + lrow] = v[nt] * inv * gv[nt] + bv[nt];
    }
}

// ---------------- GEMM (K=128,N=128) + residual + LayerNorm fused ----------------
struct GL3 {
    const float* A[3]; const short* Bp[3]; const float* bias[3];
    float* X[3]; const float* g[3]; const float* b[3];
    int M[3]; int bend[3];
};

__global__ __launch_bounds__(256) void gemm_ln(GL3 p) {
    constexpr int PITCH = 136;
    __shared__ short Alds[64 * PITCH];
    int bid = blockIdx.x;
    int di = (bid >= p.bend[0]) + (bid >= p.bend[1]);
    int bbase = di ? p.bend[di - 1] : 0;
    const float* A = p.A[di];
    const short* Bp = p.Bp[di];
    int M = p.M[di];
    int m0 = (bid - bbase) * 64;
    int tid = threadIdx.x;
    int wave = tid >> 6, lane = tid & 63;
    int lrow = lane & 15, quad = lane >> 4;

    for (int i = tid; i < 64 * 64; i += 256) {
        int r = i >> 6, kp = i & 63;
        int row = m0 + r;
        float2 v = make_float2(0.f, 0.f);
        if (row < M) v = *(const float2*)&A[(long)row * 128 + 2 * kp];
        *(unsigned*)&Alds[r * PITCH + 2 * kp] = (unsigned)f2b(v.x) | ((unsigned)f2b(v.y) << 16);
    }
    __syncthreads();
    short8 a[4];
#pragma unroll
    for (int kc = 0; kc < 4; ++kc)
        a[kc] = *(const short8*)&Alds[(wave * 16 + lrow) * PITCH + kc * 32 + quad * 8];

    floatx4 acc[8];
#pragma unroll
    for (int nt = 0; nt < 8; ++nt) acc[nt] = (floatx4){0.f, 0.f, 0.f, 0.f};
#pragma unroll
    for (int nt = 0; nt < 8; ++nt)
#pragma unroll
        for (int kc = 0; kc < 4; ++kc) {
            short8 b = *(const short8*)(Bp + (((long)nt * 4 + kc) * 64 + lane) * 8);
            acc[nt] = __builtin_amdgcn_mfma_f32_16x16x32_bf16(a[kc], b, acc[nt], 0, 0, 0);
        }
    ln_epilogue(acc, p.bias[di], p.X[di], p.g[di], p.b[di], m0, M, wave, lane);
}

// ---------------- fused FF: relu(X@W1+b1)@W2+b2 -> +X -> LN, all in one kernel ----------------
struct GF3 {
    const float* A[3]; const short* B1[3]; const float* bias1[3];
    const short* B2[3]; const float* bias2[3];
    float* X[3]; const float* g[3]; const float* b[3];
    int M[3]; int bend[3];
};

__global__ __launch_bounds__(256) void gemm_ff(GF3 p) {
    constexpr int P1 = 136, P2 = 520;           // shorts
    __shared__ short lds[64 * P2];              // 66,560 B
    int bid = blockIdx.x;
    int di = (bid >= p.bend[0]) + (bid >= p.bend[1]);
    int bbase = di ? p.bend[di - 1] : 0;
    const float* A = p.A[di];
    int M = p.M[di];
    int m0 = (bid - bbase) * 64;
    int tid = threadIdx.x;
    int wave = tid >> 6, lane = tid & 63;
    int lrow = lane & 15, quad = lane >> 4;

    // stage X rows -> bf16 LDS (P1 region)
    for (int i = tid; i < 64 * 64; i += 256) {
        int r = i >> 6, kp = i & 63;
        int row = m0 + r;
        float2 v = make_float2(0.f, 0.f);
        if (row < M) v = *(const float2*)&A[(long)row * 128 + 2 * kp];
        *(unsigned*)&lds[r * P1 + 2 * kp] = (unsigned)f2b(v.x) | ((unsigned)f2b(v.y) << 16);
    }
    __syncthreads();
    short8 a1[4];
#pragma unroll
    for (int kc = 0; kc < 4; ++kc)
        a1[kc] = *(const short8*)&lds[(wave * 16 + lrow) * P1 + kc * 32 + quad * 8];
    __syncthreads();                            // everyone has a1; LDS reusable

    // phase 1: C1 = relu(X@W1+b1) -> bf16 LDS [64][P2]
    const short* B1 = p.B1[di];
    const float* bias1 = p.bias1[di];
    int rowb = wave * 16 + quad * 4;
    for (int nt = 0; nt < 32; ++nt) {
        floatx4 acc = (floatx4){0.f, 0.f, 0.f, 0.f};
#pragma unroll
        for (int kc = 0; kc < 4; ++kc) {
            short8 b = *(const short8*)(B1 + (((long)nt * 4 + kc) * 64 + lane) * 8);
            acc = __builtin_amdgcn_mfma_f32_16x16x32_bf16(a1[kc], b, acc, 0, 0, 0);
        }
        float bv = bias1[nt * 16 + lrow];
#pragma unroll
        for (int r = 0; r < 4; ++r) {
            float v = acc[r] + bv; if (v < 0.f) v = 0.f;
            lds[(rowb + r) * P2 + nt * 16 + lrow] = (short)f2b(v);
        }
    }
    __syncthreads();

    // phase 2: C2 = C1@W2 (K=512), then residual+LN
    short8 a2[16];
#pragma unroll
    for (int kc = 0; kc < 16; ++kc)
        a2[kc] = *(const short8*)&lds[(wave * 16 + lrow) * P2 + kc * 32 + quad * 8];
    const short* B2 = p.B2[di];
    floatx4 acc2[8];
#pragma unroll
    for (int nt = 0; nt < 8; ++nt) acc2[nt] = (floatx4){0.f, 0.f, 0.f, 0.f};
#pragma unroll
    for (int nt = 0; nt < 8; ++nt)
#pragma unroll
        for (int kc = 0; kc < 16; ++kc) {
            short8 b = *(const short8*)(B2 + (((long)nt * 16 + kc) * 64 + lane) * 8);
            acc2[nt] = __builtin_amdgcn_mfma_f32_16x16x32_bf16(a2[kc], b, acc2[nt], 0, 0, 0);
        }
    ln_epilogue(acc2, p.bias2[di], p.X[di], p.g[di], p.b[di], m0, M, wave, lane);
}

// ---------------- batched causal attention, thread = (node, head, s-pair) ----------------
struct A3b { const float* q[3]; float* o[3]; int N[3]; int end[3]; };

__global__ void attn2(A3b p) {
    int idx = blockIdx.x * blockDim.x + threadIdx.x;
    if (idx >= p.end[2]) return;
    int i = (idx >= p.end[0]) + (idx >= p.end[1]);
    int base = i ? p.end[i - 1] : 0;
    int r = idx - base;
    int n = r >> 5;
    int rr = r & 31;
    int h = rr & 7, u = rr >> 3;       // u: s-pair index
    int N = p.N[i];
    const float* qkv = p.q[i];
    float* o = p.o[i];
    long rs = (long)N * 384;
    long os = (long)N * 128;
    const float* basep = qkv + (long)n * 384 + h * 16;
    float* obp = o + (long)n * 128 + h * 16;
    for (int s = 2 * u; s <= 2 * u + 1; ++s) {
        const float* qp = basep + (long)s * rs;
        float q[16];
        *(float4*)&q[0]  = *(const float4*)(qp);
        *(float4*)&q[4]  = *(const float4*)(qp + 4);
        *(float4*)&q[8]  = *(const float4*)(qp + 8);
        *(float4*)&q[12] = *(const float4*)(qp + 12);
        float sc[kT];
        float mx = -1e30f;
#pragma unroll
        for (int m = 0; m < kT; ++m) {
            if (m <= s) {
                const float* kp = basep + (long)m * rs + 128;
                float k[16];
                *(float4*)&k[0]  = *(const float4*)(kp);
                *(float4*)&k[4]  = *(const float4*)(kp + 4);
                *(float4*)&k[8]  = *(const float4*)(kp + 8);
                *(float4*)&k[12] = *(const float4*)(kp + 12);
                float d = 0.f;
#pragma unroll
                for (int j = 0; j < 16; ++j) d += q[j] * k[j];
                d *= 0.25f;
                sc[m] = d;
                mx = fmaxf(mx, d);
            }
        }
        float sum = 0.f;
#pragma unroll
        for (int m = 0; m < kT; ++m) {
            if (m <= s) { sc[m] = expf(sc[m] - mx); sum += sc[m]; }
        }
        float inv = 1.f / sum;
        float ov[16];
#pragma unroll
        for (int j = 0; j < 16; ++j) ov[j] = 0.f;
#pragma unroll
        for (int m = 0; m < kT; ++m) {
            if (m <= s) {
                const float* vp = basep + (long)m * rs + 256;
                float v[16];
                *(float4*)&v[0]  = *(const float4*)(vp);
                *(float4*)&v[4]  = *(const float4*)(vp + 4);
                *(float4*)&v[8]  = *(const float4*)(vp + 8);
                *(float4*)&v[12] = *(const float4*)(vp + 12);
                float am = sc[m] * inv;
#pragma unroll
                for (int j = 0; j < 16; ++j) ov[j] += am * v[j];
            }
        }
        float* op = obp + (long)s * os;
        *(float4*)(op)      = *(float4*)&ov[0];
        *(float4*)(op + 4)  = *(float4*)&ov[4];
        *(float4*)(op + 8)  = *(float4*)&ov[8];
        *(float4*)(op + 12) = *(float4*)&ov[12];
    }
}

// ---------------- scores: fp32 64x64 tile, 4x4 per thread, transposed LDS ----------------
__global__ __launch_bounds__(256) void score_kernel(const float* __restrict__ A, const float* __restrict__ B,
                                                    float* __restrict__ out, int M, int Nn) {
    int t = blockIdx.z;
    const float* At = A + (long)t * M * kD;
    const float* Bt = B + (long)t * Nn * kD;
    float* Ot = out + (long)t * M * Nn;
    int bm = blockIdx.y * 64, bn = blockIdx.x * 64;
    int tid = threadIdx.x;
    int cx = tid & 15, ry = tid >> 4;
    __shared__ float As[32 * 68];
    __shared__ float Bs[32 * 68];
    float acc[4][4];
#pragma unroll
    for (int i = 0; i < 4; ++i)
#pragma unroll
        for (int j = 0; j < 4; ++j) acc[i][j] = 0.f;

    for (int k0 = 0; k0 < kD; k0 += 32) {
        __syncthreads();
        for (int i = tid; i < 64 * 32; i += 256) {
            int r = i >> 5, c = i & 31;
            int am = bm + r;
            As[c * 68 + r] = (am < M) ? At[(long)am * kD + k0 + c] : 0.f;
            int bnn = bn + r;
            Bs[c * 68 + r] = (bnn < Nn) ? Bt[(long)bnn * kD + k0 + c] : 0.f;
        }
        __syncthreads();
#pragma unroll 4
        for (int k = 0; k < 32; ++k) {
            float4 a = *(const float4*)&As[k * 68 + ry * 4];
            float4 b = *(const float4*)&Bs[k * 68 + cx * 4];
            float av[4] = {a.x, a.y, a.z, a.w};
            float bv[4] = {b.x, b.y, b.z, b.w};
#pragma unroll
            for (int i = 0; i < 4; ++i)
#pragma unroll
                for (int j = 0; j < 4; ++j) acc[i][j] += av[i] * bv[j];
        }
    }
#pragma unroll
    for (int i = 0; i < 4; ++i) {
        int om = bm + ry * 4 + i;
        if (om >= M) continue;
#pragma unroll
        for (int j = 0; j < 4; ++j) {
            int on = bn + cx * 4 + j;
            if (on < Nn) Ot[(long)om * Nn + on] = acc[i][j];
        }
    }
}

// ---------------- labels scatter, both outputs ----------------
__global__ void label2(const int* __restrict__ s1, const int* __restrict__ d1, float* __restrict__ o1, int N1,
                       const int* __restrict__ s2, const int* __restrict__ d2, float* __restrict__ o2, int N2) {
    int idx = blockIdx.x * blockDim.x + threadIdx.x;
    if (idx >= 2 * kT * kE) return;
    int u = idx >> 17;
    int e = idx & (kT * kE - 1);
    int t = e >> 14;
    if (u == 0) { int s = s1[e], dd = d1[e]; o1[(long)t * kNADM * N1 + (long)s * N1 + dd] = 1.0f; }
    else        { int s = s2[e], dd = d2[e]; o2[(long)t * kNADM * N2 + (long)s * N2 + dd] = 1.0f; }
}

extern "C" void kernel_launch(void* const* d_in, const int* in_sizes, int n_in,
                              void* d_out, int out_size, void* d_ws, size_t ws_size,
                              hipStream_t stream) {
    const float* x_adm       = (const float*)d_in[0];
    const float* x_lab       = (const float*)d_in[1];
    const float* x_drug      = (const float*)d_in[2];
    const float* edge_x_did  = (const float*)d_in[3];
    const float* edge_x_took = (const float*)d_in[4];
    const float* w_proj_adm  = (const float*)d_in[5];
    const float* b_proj_adm  = (const float*)d_in[6];
    const float* w_proj_lab  = (const float*)d_in[7];
    const float* b_proj_lab  = (const float*)d_in[8];
    const float* w_proj_drug = (const float*)d_in[9];
    const float* b_proj_drug = (const float*)d_in[10];
    const float* w_proj_e    = (const float*)d_in[11];
    const float* b_proj_e    = (const float*)d_in[12];
    const float* w_proj_e4d  = (const float*)d_in[13];
    const float* b_proj_e4d  = (const float*)d_in[14];
    const float* emb_lab     = (const float*)d_in[15];
    const float* emb_drug    = (const float*)d_in[16];
    const float* gnn_w       = (const float*)d_in[17];
    const float* gnn_b       = (const float*)d_in[18];
    const float* dec_sa_in_w  = (const float*)d_in[19];
    const float* dec_sa_in_b  = (const float*)d_in[20];
    const float* dec_sa_out_w = (const float*)d_in[21];
    const float* dec_sa_out_b = (const float*)d_in[22];
    const float* dec_ca_in_w  = (const float*)d_in[23];
    const float* dec_ca_in_b  = (const float*)d_in[24];
    const float* dec_ca_out_w = (const float*)d_in[25];
    const float* dec_ca_out_b = (const float*)d_in[26];
    const float* dec_ff1_w    = (const float*)d_in[27];
    const float* dec_ff1_b    = (const float*)d_in[28];
    const float* dec_ff2_w    = (const float*)d_in[29];
    const float* dec_ff2_b    = (const float*)d_in[30];
    const float* dec_ln1_w    = (const float*)d_in[31];
    const float* dec_ln1_b    = (const float*)d_in[32];
    const float* dec_ln2_w    = (const float*)d_in[33];
    const float* dec_ln2_b    = (const float*)d_in[34];
    const float* dec_ln3_w    = (const float*)d_in[35];
    const float* dec_ln3_b    = (const float*)d_in[36];
    const int* node_id_lab  = (const int*)d_in[37];
    const int* node_id_drug = (const int*)d_in[38];
    const int* src_did      = (const int*)d_in[39];
    const int* dst_did      = (const int*)d_in[40];
    const int* src_took     = (const int*)d_in[41];
    const int* dst_took     = (const int*)d_in[42];
    const int* lbl_src_did  = (const int*)d_in[43];
    const int* lbl_dst_did  = (const int*)d_in[44];
    const int* lbl_src_took = (const int*)d_in[45];
    const int* lbl_dst_took = (const int*)d_in[46];

    float* out_f = (float*)d_out;
    const long SC1 = (long)kT * kNADM * kNLAB;    // 12,337,152
    const long SC2 = (long)kT * kNADM * kNDRUG;   // 70,352,896
    float* out_scores  = out_f;
    float* out_labels  = out_f + SC1;
    float* out_scores4 = out_f + 2 * SC1;
    float* out_labels4 = out_f + 2 * SC1 + SC2;

    // scratch arena inside d_out (scores4 + labels4 regions; both dead until the end)
    float* SCR = out_scores4;                     // 70.3M floats
    float* Sp  = out_labels4;
    const long SA_SZ = (long)kT * kNADM * kD;     // 2,097,152
    const long SL_SZ = (long)kT * kNLAB * kD;     //   771,072
    const long SD_SZ = (long)kT * kNDRUG * kD;    // 4,397,056
    float* Sa = Sp;
    float* Sl = Sa + SA_SZ;
    float* Sd = Sl + SL_SZ;                       // ends 7,265,280 (contiguous Sa|Sl|Sd)
    short* pk_base = (short*)(Sp + 7265288);
    const long PS_SA_IN = 18L * 128 * 384;
    const long PS_SA_OUT = 18L * 128 * 128;
    const long PS_CA_IN = PS_SA_IN;
    const long PS_CA_OUT = PS_SA_OUT;
    const long PS_FF1 = 18L * 128 * 512;
    const long PS_FF2 = 18L * 512 * 128;
    short* pk_sa_in  = pk_base;
    short* pk_sa_out = pk_sa_in + PS_SA_IN;
    short* pk_ca_in  = pk_sa_out + PS_SA_OUT;
    short* pk_ca_out = pk_ca_in + PS_CA_IN;
    short* pk_ff1    = pk_ca_out + PS_CA_OUT;
    short* pk_ff2    = pk_ff1 + PS_FF1;

    // GNN-phase aliases in SCR
    float* h0a = SCR;
    float* h0l = h0a + (long)kNADM * kD;
    float* h0d = h0l + (long)kNLAB * kD;
    float* Ta  = h0d + (long)kNDRUG * kD;
    float* Tl  = Ta + SA_SZ;
    float* Td  = Tl + SL_SZ;
    float* msgA1 = Td + SD_SZ;
    float* msgA2 = msgA1 + SA_SZ;
    float* msgL  = msgA2 + SA_SZ;
    float* msgD  = msgL + SL_SZ;
    const long MSG_SZ = SA_SZ * 2 + SL_SZ + SD_SZ;

    // decoder-phase aliases in SCR
    const int TNs[3] = {kT * kNADM, kT * kNLAB, kT * kNDRUG};   // 16384, 6024, 34352
    const int Ns_[3] = {kNADM, kNLAB, kNDRUG};
    const long rowsTot = (long)TNs[0] + TNs[1] + TNs[2];        // 56760
    const long roff[3] = {0, (long)TNs[0], (long)TNs[0] + TNs[1]};
    float* obase = SCR + rowsTot * 512;
    float* mbase = obase + rowsTot * 128;
    float* Xs[3] = {Sa, Sl, Sd};
    float* bb[3]; float* ob[3]; float* mb[3];
    for (int i = 0; i < 3; ++i) {
        bb[i] = SCR + roff[i] * 512;      // qkv buffer (rows x 384, alloc 512)
        ob[i] = obase + roff[i] * 128;    // attn output
        mb[i] = mbase + roff[i] * 128;    // memory (decoder input)
    }
    const int gB[3] = {(TNs[0] + 63) / 64, (TNs[1] + 63) / 64, (TNs[2] + 63) / 64}; // 256,95,537
    const int bend[3] = {gB[0], gB[0] + gB[1], gB[0] + gB[1] + gB[2]};              // 256,351,888
    const int gTot = bend[2];
    // attn ends: nodes * H * 4 s-pairs
    const int aend[3] = {Ns_[0] * 32, (Ns_[0] + Ns_[1]) * 32, (Ns_[0] + Ns_[1] + Ns_[2]) * 32};
    const int aBlk = (aend[2] + 255) / 256;

    // ---- pack all decoder weights in one launch ----
    {
        PK6 pk;
        const float* Ws[6] = {dec_sa_in_w, dec_sa_out_w, dec_ca_in_w, dec_ca_out_w, dec_ff1_w, dec_ff2_w};
        short* outs[6] = {pk_sa_in, pk_sa_out, pk_ca_in, pk_ca_out, pk_ff1, pk_ff2};
        int Ks[6] = {128, 128, 128, 128, 128, 512};
        int Nss[6] = {384, 128, 384, 128, 512, 128};
        long tots[6] = {PS_SA_IN, PS_SA_OUT, PS_CA_IN, PS_CA_OUT, PS_FF1, PS_FF2};
        int cum = 0;
        for (int i = 0; i < 6; ++i) {
            pk.W[i] = Ws[i]; pk.out[i] = outs[i]; pk.K[i] = Ks[i]; pk.N[i] = Nss[i]; pk.tot[i] = tots[i];
            cum += (int)((tots[i] + 255) / 256);
            pk.bend[i] = cum;
        }
        pack6<<<cum, 256, 0, stream>>>(pk);
    }

    // ---- node projections (merged) ----
    proj3<<<kNADM + kNLAB + kNDRUG, kD, 0, stream>>>(
        x_adm, w_proj_adm, b_proj_adm,
        x_lab, w_proj_lab, b_proj_lab, emb_lab, node_id_lab,
        x_drug, w_proj_drug, b_proj_drug, emb_drug, node_id_drug,
        h0a, h0l, h0d);

    // ---- GNN: 2 layers ----
    for (int l = 0; l < 2; ++l) {
        hipMemsetAsync((void*)msgA1, 0, (size_t)MSG_SZ * sizeof(float), stream);
        const float *ha, *hl, *hd;
        long sa, sl, sd;
        float *oa, *ol, *od;
        if (l == 0) { ha = h0a; hl = h0l; hd = h0d; sa = sl = sd = 0;
                      oa = Ta; ol = Tl; od = Td; }
        else        { ha = Ta; hl = Tl; hd = Td;
                      sa = (long)kNADM * kD; sl = (long)kNLAB * kD; sd = (long)kNDRUG * kD;
                      oa = Sa; ol = Sl; od = Sd; }
        M2 m;
        m.ex[0] = edge_x_did;  m.ek[0] = 2; m.src[0] = src_did;  m.dst[0] = dst_did;
        m.we[0] = w_proj_e;    m.be[0] = b_proj_e;
        m.hS[0] = ha; m.hSs[0] = sa; m.hD[0] = hl; m.hDs[0] = sl;
        m.msgDst[0] = msgL; m.Ndst[0] = kNLAB; m.msgSrc[0] = msgA1; m.Nsrc[0] = kNADM;
        m.ex[1] = edge_x_took; m.ek[1] = 7; m.src[1] = src_took; m.dst[1] = dst_took;
        m.we[1] = w_proj_e4d;  m.be[1] = b_proj_e4d;
        m.hS[1] = ha; m.hSs[1] = sa; m.hD[1] = hd; m.hDs[1] = sd;
        m.msgDst[1] = msgD; m.Ndst[1] = kNDRUG; m.msgSrc[1] = msgA2; m.Nsrc[1] = kNADM;
        msg2<<<2 * kT * kE, kD, 0, stream>>>(m);
        GD gd;
        gd.m1 = msgA1; gd.m2 = msgA2; gd.mL = msgL; gd.mD = msgD;
        gd.ha = ha; gd.hl = hl; gd.hd = hd;
        gd.sa = sa; gd.sl = sl; gd.sd = sd;
        gd.gw = gnn_w; gd.gb = gnn_b; gd.l = l;
        gd.oa = oa; gd.ol = ol; gd.od = od;
        gdense<<<1024 + 384 + 2152, 256, 0, stream>>>(gd);
    }

    // ---- positional encoding over contiguous Sa|Sl|Sd ----
    pe_all<<<(int)rowsTot, kD, 0, stream>>>(Sa, TNs[0], TNs[0] + TNs[1], kNADM, kNLAB, kNDRUG);

    // ---- memory copy (decoder input) ----
    copy4<<<(int)((rowsTot * 32 + 255) / 256), 256, 0, stream>>>((float4*)mbase, (const float4*)Sa, rowsTot * 32);

    // ---- decoders: all 3 batched per launch, 7 launches per layer ----
    for (int l = 0; l < kL; ++l) {
        long wi[3] = {(long)l, (long)(kL + l), (long)(2 * kL + l)};
        A3b at;
        for (int i = 0; i < 3; ++i) { at.q[i] = bb[i]; at.o[i] = ob[i]; at.N[i] = Ns_[i]; at.end[i] = aend[i]; }

        // self-attention qkv (3 segments, NT=24)
        {
            G6 g;
            for (int i = 0; i < 3; ++i) {
                g.A[i] = Xs[i]; g.Bp[i] = pk_sa_in + wi[i] * 49152;
                g.bias[i] = dec_sa_in_b + wi[i] * 384; g.C[i] = bb[i];
                g.M[i] = TNs[i]; g.bend[i] = bend[i]; g.NT[i] = 24; g.ldc[i] = 384;
            }
            for (int i = 3; i < 6; ++i) { g.bend[i] = bend[2]; g.A[i] = g.A[2]; g.Bp[i] = g.Bp[2];
                g.bias[i] = g.bias[2]; g.C[i] = g.C[2]; g.M[i] = g.M[2]; g.NT[i] = 24; g.ldc[i] = 384; }
            gemm_rtN<<<gTot, 256, 0, stream>>>(g);
        }
        attn2<<<aBlk, 256, 0, stream>>>(at);
        // sa_out + residual + LN1
        {
            GL3 gl;
            for (int i = 0; i < 3; ++i) {
                gl.A[i] = ob[i]; gl.Bp[i] = pk_sa_out + wi[i] * 16384;
                gl.bias[i] = dec_sa_out_b + wi[i] * kD;
                gl.X[i] = Xs[i]; gl.g[i] = dec_ln1_w + wi[i] * kD; gl.b[i] = dec_ln1_b + wi[i] * kD;
                gl.M[i] = TNs[i]; gl.bend[i] = bend[i];
            }
            gemm_ln<<<gTot, 256, 0, stream>>>(gl);
        }
        // cross-attention qkv: q from X (NT=8) + kv from memory (NT=16), 6 segments in one launch
        {
            G6 g;
            for (int i = 0; i < 3; ++i) {
                g.A[i] = Xs[i]; g.Bp[i] = pk_ca_in + wi[i] * 49152;
                g.bias[i] = dec_ca_in_b + wi[i] * 384; g.C[i] = bb[i];
                g.M[i] = TNs[i]; g.bend[i] = bend[i]; g.NT[i] = 8; g.ldc[i] = 384;
            }
            for (int i = 0; i < 3; ++i) {
                g.A[3 + i] = mb[i]; g.Bp[3 + i] = pk_ca_in + wi[i] * 49152 + 16384;
                g.bias[3 + i] = dec_ca_in_b + wi[i] * 384 + 128; g.C[3 + i] = bb[i] + 128;
                g.M[3 + i] = TNs[i]; g.bend[3 + i] = bend[2] + bend[i]; g.NT[3 + i] = 16; g.ldc[3 + i] = 384;
            }
            gemm_rtN<<<2 * gTot, 256, 0, stream>>>(g);
        }
        attn2<<<aBlk, 256, 0, stream>>>(at);
        // ca_out + residual + LN2
        {
            GL3 gl;
            for (int i = 0; i < 3; ++i) {
                gl.A[i] = ob[i]; gl.Bp[i] = pk_ca_out + wi[i] * 16384;
                gl.bias[i] = dec_ca_out_b + wi[i] * kD;
                gl.X[i] = Xs[i]; gl.g[i] = dec_ln2_w + wi[i] * kD; gl.b[i] = dec_ln2_b + wi[i] * kD;
                gl.M[i] = TNs[i]; gl.bend[i] = bend[i];
            }
            gemm_ln<<<gTot, 256, 0, stream>>>(gl);
        }
        // fused FF1+FF2 + residual + LN3
        {
            GF3 gf;
            for (int i = 0; i < 3; ++i) {
                gf.A[i] = Xs[i];
                gf.B1[i] = pk_ff1 + wi[i] * 65536; gf.bias1[i] = dec_ff1_b + wi[i] * kFF;
                gf.B2[i] = pk_ff2 + wi[i] * 65536; gf.bias2[i] = dec_ff2_b + wi[i] * kD;
                gf.X[i] = Xs[i]; gf.g[i] = dec_ln3_w + wi[i] * kD; gf.b[i] = dec_ln3_b + wi[i] * kD;
                gf.M[i] = TNs[i]; gf.bend[i] = bend[i];
            }
            gemm_ff<<<gTot, 256, 0, stream>>>(gf);
        }
    }

    // scores (adm x lab)
    score_kernel<<<dim3((kNLAB + 63) / 64, kNADM / 64, kT), 256, 0, stream>>>(Sa, Sl, out_scores, kNADM, kNLAB);
    // scores4 (adm x drug): writes over SCR (dead), reads Sa/Sd — disjoint
    score_kernel<<<dim3((kNDRUG + 63) / 64, kNADM / 64, kT), 256, 0, stream>>>(Sa, Sd, out_scores4, kNADM, kNDRUG);
    // labels (memsets clobber scratch incl. Sa/Sl/Sd + packed weights, all dead now)
    hipMemsetAsync((void*)out_labels, 0, (size_t)SC1 * sizeof(float), stream);
    hipMemsetAsync((void*)out_labels4, 0, (size_t)SC2 * sizeof(float), stream);
    label2<<<(2 * kT * kE + 255) / 256, 256, 0, stream>>>(
        lbl_src_did, lbl_dst_did, out_labels, kNLAB,
        lbl_src_took, lbl_dst_took, out_labels4, kNDRUG);

    (void)in_sizes; (void)n_in; (void)out_size; (void)d_ws; (void)ws_size;
}

// Round 3
// 2727.086 us; speedup vs baseline: 2.3664x; 1.1710x over previous
//
#include <hip/hip_runtime.h>
#include <hip/hip_bf16.h>

// problem constants
#define kT 8
#define kD 128
#define kH 8
#define kHD 16
#define kFF 512
#define kL 6
#define kNADM 2048
#define kNLAB 753
#define kNDRUG 4294
#define kE 16384

// CSR slot bases: c0 lab<-did, c1 adm<-did, c2 drug<-took, c3 adm<-took
#define B_C1 6024
#define B_C2 22408
#define B_C3 56760
#define CSR_SLOTS 73144

typedef __attribute__((ext_vector_type(8))) short short8;
typedef __attribute__((ext_vector_type(4))) float floatx4;

// round-to-nearest-even fp32 -> bf16 bits
__device__ __forceinline__ unsigned short f2b(float f) {
    unsigned x = __float_as_uint(f);
    unsigned r = (x + 0x7fffu + ((x >> 16) & 1u)) >> 16;
    return (unsigned short)r;
}

__device__ __forceinline__ float quad_reduce16(float v) {
    v += __shfl_xor(v, 1);
    v += __shfl_xor(v, 2);
    v += __shfl_xor(v, 4);
    v += __shfl_xor(v, 8);
    return v;
}

__device__ __forceinline__ float4 pe4v(int t, int d0) {
    const float cc = 9.210340371976184f / 128.f;
    float a0 = (float)t * expf(-(float)d0 * cc);
    float a1 = (float)t * expf(-(float)(d0 + 2) * cc);
    return make_float4(sinf(a0), cosf(a0), sinf(a1), cosf(a1));
}

// ---------------- merged weight pack: fp32 [slices][K][N] -> bf16 B-fragment order ----------------
struct PK6 { const float* W[6]; short* out[6]; int K[6]; int N[6]; long tot[6]; int bend[6]; };

__global__ void pack6(PK6 p) {
    int bid = blockIdx.x;
    int di = 0;
    while (bid >= p.bend[di]) ++di;
    int bstart = di ? p.bend[di - 1] : 0;
    long idx = (long)(bid - bstart) * 256 + threadIdx.x;
    if (idx >= p.tot[di]) return;
    int K = p.K[di], N = p.N[di];
    long per = (long)K * N;
    long s = idx / per, r = idx % per;
    int k = (int)(r / N), n = (int)(r % N);
    int tile = n >> 4, kcg = k >> 5, quad = (k >> 3) & 3, j = k & 7;
    int lane = quad * 16 + (n & 15);
    long pidx = (((long)tile * (K >> 5) + kcg) * 64 + lane) * 8 + j;
    p.out[di][s * per + pidx] = (short)f2b(p.W[di][idx]);
}

// ---------------- merged node projections ----------------
__global__ void proj3(const float* __restrict__ xa, const float* __restrict__ wa, const float* __restrict__ ba,
                      const float* __restrict__ xl, const float* __restrict__ wl, const float* __restrict__ bl,
                      const float* __restrict__ el, const int* __restrict__ nl,
                      const float* __restrict__ xd, const float* __restrict__ wd, const float* __restrict__ bd,
                      const float* __restrict__ ed, const int* __restrict__ nd,
                      float* __restrict__ oa, float* __restrict__ ol, float* __restrict__ od) {
    int bid = blockIdx.x, d = threadIdx.x;
    const float* x; const float* w; const float* b; const float* emb = nullptr;
    const int* nid = nullptr; float* out; int IK, n;
    if (bid < kNADM) { n = bid; x = xa; w = wa; b = ba; out = oa; IK = 8; }
    else if (bid < kNADM + kNLAB) { n = bid - kNADM; x = xl; w = wl; b = bl; emb = el; nid = nl; out = ol; IK = 2; }
    else { n = bid - kNADM - kNLAB; x = xd; w = wd; b = bd; emb = ed; nid = nd; out = od; IK = 8; }
    float acc = b[d];
    for (int k = 0; k < IK; ++k) acc += x[(long)n * IK + k] * w[k * kD + d];
    if (emb) acc += emb[(long)nid[n] * kD + d];
    out[(long)n * kD + d] = acc;
}

// ---------------- CSR build: hist -> scan -> scatter (topology is launch-invariant) ----------------
__global__ void csr_hist(const int* __restrict__ dd, const int* __restrict__ sd,
                         const int* __restrict__ dt, const int* __restrict__ st,
                         int* __restrict__ cnt) {
    int idx = blockIdx.x * 256 + threadIdx.x;
    if (idx >= 4 * kT * kE) return;
    int c = idx >> 17, e = idx & (kT * kE - 1), t = e >> 14;
    int slot;
    if (c == 0)      slot = t * 753 + dd[e];
    else if (c == 1) slot = B_C1 + t * 2048 + sd[e];
    else if (c == 2) slot = B_C2 + t * 4294 + dt[e];
    else             slot = B_C3 + t * 2048 + st[e];
    atomicAdd(&cnt[slot], 1);
}

__global__ __launch_bounds__(256) void csr_scan(const int* __restrict__ cnt,
                                                int* __restrict__ off, int* __restrict__ cur) {
    int seg = blockIdx.x;          // 32 segments = (c,t)
    int c = seg >> 3, t = seg & 7;
    int NB = (c == 0) ? 753 : (c == 2) ? 4294 : 2048;
    int base = (c == 0) ? 0 : (c == 1) ? B_C1 : (c == 2) ? B_C2 : B_C3;
    int s0 = base + t * NB;
    __shared__ int part[256];
    int tid = threadIdx.x;
    int carry = 0;
    for (int ch = 0; ch < NB; ch += 256) {
        int i = ch + tid;
        int v = (i < NB) ? cnt[s0 + i] : 0;
        part[tid] = v;
        __syncthreads();
        for (int st = 1; st < 256; st <<= 1) {
            int a = (tid >= st) ? part[tid - st] : 0;
            __syncthreads();
            part[tid] += a;
            __syncthreads();
        }
        if (i < NB) { int ex = carry + part[tid] - v; off[s0 + i] = ex; cur[s0 + i] = ex; }
        carry += part[255];
        __syncthreads();
    }
}

__global__ void csr_scatter(const int* __restrict__ dd, const int* __restrict__ sd,
                            const int* __restrict__ dt, const int* __restrict__ st,
                            int* __restrict__ cur, int* __restrict__ lists) {
    int idx = blockIdx.x * 256 + threadIdx.x;
    if (idx >= 4 * kT * kE) return;
    int c = idx >> 17, e = idx & (kT * kE - 1), t = e >> 14;
    int slot;
    if (c == 0)      slot = t * 753 + dd[e];
    else if (c == 1) slot = B_C1 + t * 2048 + sd[e];
    else if (c == 2) slot = B_C2 + t * 4294 + dt[e];
    else             slot = B_C3 + t * 2048 + st[e];
    int pos = atomicAdd(&cur[slot], 1);
    lists[c * (kT * kE) + t * kE + pos] = e;
}

// ---------------- CSR gather: msg[t,v,:] = sum relu(h_src + e), no atomics ----------------
template<int EK>
__device__ __forceinline__ float gath(const int* __restrict__ lp, int deg,
        const int* __restrict__ nbA, const float* __restrict__ exB,
        const float* __restrict__ ww, float ber, const float* __restrict__ hb, int d) {
    float wr[EK];
#pragma unroll
    for (int k = 0; k < EK; ++k) wr[k] = ww[k * kD + d];
    float acc = 0.f;
    for (int i = 0; i < deg; ++i) {
        int e = lp[i];
        int u = nbA[e];
        const float* ex = exB + (long)e * EK;
        float ev = ber;
#pragma unroll
        for (int k = 0; k < EK; ++k) ev += ex[k] * wr[k];
        float m = hb[(long)u << 7] + ev;
        acc += (m > 0.f) ? m : 0.f;
    }
    return acc;
}

struct GG {
    const float* ha; const float* hl; const float* hd;
    long sa, sl, sd;
    const float* exd; const float* ext;
    const float* we; const float* be; const float* we4; const float* be4;
    const int* srcd; const int* dstd; const int* srct; const int* dstt;
    const int* off; const int* cnt; const int* lists;
    float* msgL; float* msgA1; float* msgD; float* msgA2;
};

__global__ __launch_bounds__(128) void csr_gather(GG p) {
    int slot = blockIdx.x, d = threadIdx.x;
    int c, t, v, NB;
    const float* hp; long hs; const float* exB; int ek;
    const float* ww; const float* bb_; const int* nbA; float* out; int Nout;
    if (slot < B_C1)      { c = 0; NB = 753;  int rem = slot;        t = rem / NB; v = rem - t * NB;
                            hp = p.ha; hs = p.sa; exB = p.exd; ek = 2; ww = p.we;  bb_ = p.be;
                            nbA = p.srcd; out = p.msgL;  Nout = kNLAB; }
    else if (slot < B_C2) { c = 1; NB = 2048; int rem = slot - B_C1; t = rem >> 11; v = rem & 2047;
                            hp = p.hl; hs = p.sl; exB = p.exd; ek = 2; ww = p.we;  bb_ = p.be;
                            nbA = p.dstd; out = p.msgA1; Nout = kNADM; }
    else if (slot < B_C3) { c = 2; NB = 4294; int rem = slot - B_C2; t = rem / NB; v = rem - t * NB;
                            hp = p.ha; hs = p.sa; exB = p.ext; ek = 7; ww = p.we4; bb_ = p.be4;
                            nbA = p.srct; out = p.msgD;  Nout = kNDRUG; }
    else                  { c = 3; NB = 2048; int rem = slot - B_C3; t = rem >> 11; v = rem & 2047;
                            hp = p.hd; hs = p.sd; exB = p.ext; ek = 7; ww = p.we4; bb_ = p.be4;
                            nbA = p.dstt; out = p.msgA2; Nout = kNADM; }
    float ber = bb_[d];
    int deg = p.cnt[slot];
    int o0 = p.off[slot];
    const int* lp = p.lists + c * (kT * kE) + t * kE + o0;
    const float* hb = hp + t * hs + d;
    float acc = (ek == 2) ? gath<2>(lp, deg, nbA, exB, ww, ber, hb, d)
                          : gath<7>(lp, deg, nbA, exB, ww, ber, hb, d);
    out[(((long)t * Nout + v) << 7) + d] = acc;
}

// ---------------- merged GNN dense (+ optional PE & membuf fusion on last layer) ----------------
struct GD {
    const float* m1; const float* m2; const float* mL; const float* mD;
    const float* ha; const float* hl; const float* hd;
    long sa, sl, sd;
    const float* gw; const float* gb; int l;
    float* oa; float* ol; float* od;
    float* o2a; float* o2l; float* o2d; int pe;
};

__global__ __launch_bounds__(256) void gdense(GD p) {
    int bid = blockIdx.x;
    int tid = threadIdx.x;
    int dq = tid & 31, rg = tid >> 5;
    __shared__ float R1[16][kD], R2[16][kD];
    if (bid < 1024) {
        // ---- adm path ----
        int t = bid >> 7, rt = bid & 127;
        int r0 = rt * 16;
        for (int x = tid; x < 16 * kD; x += 256) {
            int r = x >> 7, dd2 = x & 127;
            long n = r0 + r;
            long o = (((long)t * kNADM + n) << 7) + dd2;
            float h = p.ha[t * p.sa + (n << 7) + dd2];
            R1[r][dd2] = p.m1[o] + h;
            R2[r][dd2] = p.m2[o] + h;
        }
        __syncthreads();
        long w1o = ((long)t * 2 + p.l) * 4 + 1, w3o = w1o + 2;
        const float* W1 = p.gw + (w1o << 14);
        const float* W3 = p.gw + (w3o << 14);
        float acc0[4], acc1[4];
#pragma unroll
        for (int j = 0; j < 4; ++j) {
            float bv = p.gb[(w1o << 7) + dq * 4 + j] + p.gb[(w3o << 7) + dq * 4 + j];
            acc0[j] = bv; acc1[j] = bv;
        }
        const float* P0 = &R1[rg * 2][0];
        const float* P1 = &R1[rg * 2 + 1][0];
        const float* Q0 = &R2[rg * 2][0];
        const float* Q1 = &R2[rg * 2 + 1][0];
#pragma unroll 2
        for (int k = 0; k < kD; ++k) {
            float4 wa4 = *(const float4*)&W1[(k << 7) + dq * 4];
            float4 wb4 = *(const float4*)&W3[(k << 7) + dq * 4];
            float p0 = P0[k], p1 = P1[k], q0 = Q0[k], q1 = Q1[k];
            acc0[0] += p0 * wa4.x + q0 * wb4.x; acc0[1] += p0 * wa4.y + q0 * wb4.y;
            acc0[2] += p0 * wa4.z + q0 * wb4.z; acc0[3] += p0 * wa4.w + q0 * wb4.w;
            acc1[0] += p1 * wa4.x + q1 * wb4.x; acc1[1] += p1 * wa4.y + q1 * wb4.y;
            acc1[2] += p1 * wa4.z + q1 * wb4.z; acc1[3] += p1 * wa4.w + q1 * wb4.w;
        }
        long n0 = r0 + rg * 2;
        float4 pv = make_float4(0.f, 0.f, 0.f, 0.f);
        if (p.pe) pv = pe4v(t, dq * 4);
        long o0 = (((long)t * kNADM + n0) << 7) + dq * 4;
        long o1 = (((long)t * kNADM + n0 + 1) << 7) + dq * 4;
        float4 v;
        v.x = fmaxf(acc0[0], 0.f) + pv.x; v.y = fmaxf(acc0[1], 0.f) + pv.y;
        v.z = fmaxf(acc0[2], 0.f) + pv.z; v.w = fmaxf(acc0[3], 0.f) + pv.w;
        *(float4*)&p.oa[o0] = v;
        if (p.pe) *(float4*)&p.o2a[o0] = v;
        v.x = fmaxf(acc1[0], 0.f) + pv.x; v.y = fmaxf(acc1[1], 0.f) + pv.y;
        v.z = fmaxf(acc1[2], 0.f) + pv.z; v.w = fmaxf(acc1[3], 0.f) + pv.w;
        *(float4*)&p.oa[o1] = v;
        if (p.pe) *(float4*)&p.o2a[o1] = v;
    } else {
        // ---- generic path (lab / drug) ----
        const float* msg; const float* hin; long hs; float* out; float* out2; int N, type, t, rt;
        if (bid < 1408) { int b = bid - 1024; t = b / 48;  rt = b % 48;  msg = p.mL; hin = p.hl; hs = p.sl; out = p.ol; out2 = p.o2l; N = kNLAB;  type = 0; }
        else            { int b = bid - 1408; t = b / 269; rt = b % 269; msg = p.mD; hin = p.hd; hs = p.sd; out = p.od; out2 = p.o2d; N = kNDRUG; type = 2; }
        int r0 = rt * 16;
        for (int x = tid; x < 16 * kD; x += 256) {
            int r = x >> 7, dd2 = x & 127;
            int n = r0 + r;
            R1[r][dd2] = (n < N)
                ? msg[(((long)t * N + n) << 7) + dd2] + hin[t * hs + ((long)n << 7) + dd2]
                : 0.f;
        }
        __syncthreads();
        long wo = ((long)t * 2 + p.l) * 4 + type;
        const float* W = p.gw + (wo << 14);
        const float* bp = p.gb + (wo << 7) + dq * 4;
        float acc0[4], acc1[4];
#pragma unroll
        for (int j = 0; j < 4; ++j) { acc0[j] = bp[j]; acc1[j] = bp[j]; }
        const float* Rp0 = &R1[rg * 2][0];
        const float* Rp1 = &R1[rg * 2 + 1][0];
#pragma unroll 4
        for (int k = 0; k < kD; ++k) {
            float4 w4 = *(const float4*)&W[(k << 7) + dq * 4];
            float a0 = Rp0[k], a1 = Rp1[k];
            acc0[0] += a0 * w4.x; acc0[1] += a0 * w4.y; acc0[2] += a0 * w4.z; acc0[3] += a0 * w4.w;
            acc1[0] += a1 * w4.x; acc1[1] += a1 * w4.y; acc1[2] += a1 * w4.z; acc1[3] += a1 * w4.w;
        }
        int n0 = r0 + rg * 2;
        float4 pv = make_float4(0.f, 0.f, 0.f, 0.f);
        if (p.pe) pv = pe4v(t, dq * 4);
        if (n0 < N) {
            long oo = (((long)t * N + n0) << 7) + dq * 4;
            float4 v;
            v.x = fmaxf(acc0[0], 0.f) + pv.x; v.y = fmaxf(acc0[1], 0.f) + pv.y;
            v.z = fmaxf(acc0[2], 0.f) + pv.z; v.w = fmaxf(acc0[3], 0.f) + pv.w;
            *(float4*)&out[oo] = v;
            if (p.pe) *(float4*)&out2[oo] = v;
        }
        if (n0 + 1 < N) {
            long oo = (((long)t * N + n0 + 1) << 7) + dq * 4;
            float4 v;
            v.x = fmaxf(acc1[0], 0.f) + pv.x; v.y = fmaxf(acc1[1], 0.f) + pv.y;
            v.z = fmaxf(acc1[2], 0.f) + pv.z; v.w = fmaxf(acc1[3], 0.f) + pv.w;
            *(float4*)&out[oo] = v;
            if (p.pe) *(float4*)&out2[oo] = v;
        }
    }
}

// ---------------- batched runtime-NT MFMA GEMM (K=128), up to 6 segments ----------------
struct G6 {
    const float* A[6]; const short* Bp[6]; const float* bias[6];
    float* C[6]; int M[6]; int bend[6]; int NT[6]; int ldc[6];
};

__global__ __launch_bounds__(256) void gemm_rtN(G6 p) {
    constexpr int PITCH = 136;
    __shared__ short Alds[64 * PITCH];
    int bid = blockIdx.x;
    int di = 0;
    while (bid >= p.bend[di]) ++di;
    int bbase = di ? p.bend[di - 1] : 0;
    const float* A = p.A[di];
    const short* Bp = p.Bp[di];
    const float* bias = p.bias[di];
    float* C = p.C[di];
    int M = p.M[di], NT = p.NT[di], ldc = p.ldc[di];
    int m0 = (bid - bbase) * 64;
    int tid = threadIdx.x;
    int wave = tid >> 6, lane = tid & 63;
    int lrow = lane & 15, quad = lane >> 4;

    for (int i = tid; i < 64 * 64; i += 256) {
        int r = i >> 6, kp = i & 63;
        int row = m0 + r;
        float2 v = make_float2(0.f, 0.f);
        if (row < M) v = *(const float2*)&A[(long)row * 128 + 2 * kp];
        *(unsigned*)&Alds[r * PITCH + 2 * kp] = (unsigned)f2b(v.x) | ((unsigned)f2b(v.y) << 16);
    }
    __syncthreads();
    short8 a[4];
#pragma unroll
    for (int kc = 0; kc < 4; ++kc)
        a[kc] = *(const short8*)&Alds[(wave * 16 + lrow) * PITCH + kc * 32 + quad * 8];

    for (int nt = 0; nt < NT; ++nt) {
        floatx4 acc = (floatx4){0.f, 0.f, 0.f, 0.f};
#pragma unroll
        for (int kc = 0; kc < 4; ++kc) {
            short8 b = *(const short8*)(Bp + (((long)nt * 4 + kc) * 64 + lane) * 8);
            acc = __builtin_amdgcn_mfma_f32_16x16x32_bf16(a[kc], b, acc, 0, 0, 0);
        }
        int col = nt * 16 + lrow;
        float bv = bias[col];
#pragma unroll
        for (int r = 0; r < 4; ++r) {
            int row = m0 + wave * 16 + quad * 4 + r;
            if (row < M) C[(long)row * ldc + col] = acc[r] + bv;
        }
    }
}

// ---------------- LN epilogue shared by gemm_ln / gemm_ff ----------------
__device__ __forceinline__ void ln_epilogue(floatx4* acc, const float* __restrict__ bias,
        float* __restrict__ X, const float* __restrict__ g, const float* __restrict__ b,
        int m0, int M, int wave, int lane) {
    int lrow = lane & 15, quad = lane >> 4;
    float gv[8], bv[8], biv[8];
#pragma unroll
    for (int nt = 0; nt < 8; ++nt) {
        int col = nt * 16 + lrow;
        gv[nt] = g[col]; bv[nt] = b[col]; biv[nt] = bias[col];
    }
#pragma unroll
    for (int r = 0; r < 4; ++r) {
        int row = m0 + wave * 16 + quad * 4 + r;
        if (row >= M) continue;                 // uniform per 16-lane quad
        long ro = (long)row * 128;
        float v[8]; float s = 0.f;
#pragma unroll
        for (int nt = 0; nt < 8; ++nt) {
            v[nt] = acc[nt][r] + biv[nt] + X[ro + nt * 16 + lrow];
            s += v[nt];
        }
        s = quad_reduce16(s);
        float mu = s * (1.f / 128.f);
        float vs = 0.f;
#pragma unroll
        for (int nt = 0; nt < 8; ++nt) { v[nt] -= mu; vs += v[nt] * v[nt]; }
        vs = quad_reduce16(vs);
        float inv = rsqrtf(vs * (1.f / 128.f) + 1e-5f);
#pragma unroll
        for (int nt = 0; nt < 8; ++nt)
            X[ro + nt * 16 + lrow] = v[nt] * inv * gv[nt] + bv[nt];
    }
}

// ---------------- GEMM (K=128,N=128) + residual + LayerNorm fused ----------------
struct GL3 {
    const float* A[3]; const short* Bp[3]; const float* bias[3];
    float* X[3]; const float* g[3]; const float* b[3];
    int M[3]; int bend[3];
};

__global__ __launch_bounds__(256) void gemm_ln(GL3 p) {
    constexpr int PITCH = 136;
    __shared__ short Alds[64 * PITCH];
    int bid = blockIdx.x;
    int di = (bid >= p.bend[0]) + (bid >= p.bend[1]);
    int bbase = di ? p.bend[di - 1] : 0;
    const float* A = p.A[di];
    const short* Bp = p.Bp[di];
    int M = p.M[di];
    int m0 = (bid - bbase) * 64;
    int tid = threadIdx.x;
    int wave = tid >> 6, lane = tid & 63;
    int lrow = lane & 15, quad = lane >> 4;

    for (int i = tid; i < 64 * 64; i += 256) {
        int r = i >> 6, kp = i & 63;
        int row = m0 + r;
        float2 v = make_float2(0.f, 0.f);
        if (row < M) v = *(const float2*)&A[(long)row * 128 + 2 * kp];
        *(unsigned*)&Alds[r * PITCH + 2 * kp] = (unsigned)f2b(v.x) | ((unsigned)f2b(v.y) << 16);
    }
    __syncthreads();
    short8 a[4];
#pragma unroll
    for (int kc = 0; kc < 4; ++kc)
        a[kc] = *(const short8*)&Alds[(wave * 16 + lrow) * PITCH + kc * 32 + quad * 8];

    floatx4 acc[8];
#pragma unroll
    for (int nt = 0; nt < 8; ++nt) acc[nt] = (floatx4){0.f, 0.f, 0.f, 0.f};
#pragma unroll
    for (int nt = 0; nt < 8; ++nt)
#pragma unroll
        for (int kc = 0; kc < 4; ++kc) {
            short8 b = *(const short8*)(Bp + (((long)nt * 4 + kc) * 64 + lane) * 8);
            acc[nt] = __builtin_amdgcn_mfma_f32_16x16x32_bf16(a[kc], b, acc[nt], 0, 0, 0);
        }
    ln_epilogue(acc, p.bias[di], p.X[di], p.g[di], p.b[di], m0, M, wave, lane);
}

// ---------------- fused FF: relu(X@W1+b1)@W2+b2 -> +X -> LN ----------------
struct GF3 {
    const float* A[3]; const short* B1[3]; const float* bias1[3];
    const short* B2[3]; const float* bias2[3];
    float* X[3]; const float* g[3]; const float* b[3];
    int M[3]; int bend[3];
};

__global__ __launch_bounds__(256) void gemm_ff(GF3 p) {
    constexpr int P1 = 136, P2 = 520;           // shorts
    __shared__ short lds[64 * P2];              // 66,560 B
    int bid = blockIdx.x;
    int di = (bid >= p.bend[0]) + (bid >= p.bend[1]);
    int bbase = di ? p.bend[di - 1] : 0;
    const float* A = p.A[di];
    int M = p.M[di];
    int m0 = (bid - bbase) * 64;
    int tid = threadIdx.x;
    int wave = tid >> 6, lane = tid & 63;
    int lrow = lane & 15, quad = lane >> 4;

    for (int i = tid; i < 64 * 64; i += 256) {
        int r = i >> 6, kp = i & 63;
        int row = m0 + r;
        float2 v = make_float2(0.f, 0.f);
        if (row < M) v = *(const float2*)&A[(long)row * 128 + 2 * kp];
        *(unsigned*)&lds[r * P1 + 2 * kp] = (unsigned)f2b(v.x) | ((unsigned)f2b(v.y) << 16);
    }
    __syncthreads();
    short8 a1[4];
#pragma unroll
    for (int kc = 0; kc < 4; ++kc)
        a1[kc] = *(const short8*)&lds[(wave * 16 + lrow) * P1 + kc * 32 + quad * 8];
    __syncthreads();                            // everyone has a1; LDS reusable

    const short* B1 = p.B1[di];
    const float* bias1 = p.bias1[di];
    int rowb = wave * 16 + quad * 4;
    for (int nt = 0; nt < 32; ++nt) {
        floatx4 acc = (floatx4){0.f, 0.f, 0.f, 0.f};
#pragma unroll
        for (int kc = 0; kc < 4; ++kc) {
            short8 b = *(const short8*)(B1 + (((long)nt * 4 + kc) * 64 + lane) * 8);
            acc = __builtin_amdgcn_mfma_f32_16x16x32_bf16(a1[kc], b, acc, 0, 0, 0);
        }
        float bv = bias1[nt * 16 + lrow];
#pragma unroll
        for (int r = 0; r < 4; ++r) {
            float v = acc[r] + bv; if (v < 0.f) v = 0.f;
            lds[(rowb + r) * P2 + nt * 16 + lrow] = (short)f2b(v);
        }
    }
    __syncthreads();

    short8 a2[16];
#pragma unroll
    for (int kc = 0; kc < 16; ++kc)
        a2[kc] = *(const short8*)&lds[(wave * 16 + lrow) * P2 + kc * 32 + quad * 8];
    const short* B2 = p.B2[di];
    floatx4 acc2[8];
#pragma unroll
    for (int nt = 0; nt < 8; ++nt) acc2[nt] = (floatx4){0.f, 0.f, 0.f, 0.f};
#pragma unroll
    for (int nt = 0; nt < 8; ++nt)
#pragma unroll
        for (int kc = 0; kc < 16; ++kc) {
            short8 b = *(const short8*)(B2 + (((long)nt * 16 + kc) * 64 + lane) * 8);
            acc2[nt] = __builtin_amdgcn_mfma_f32_16x16x32_bf16(a2[kc], b, acc2[nt], 0, 0, 0);
        }
    ln_epilogue(acc2, p.bias2[di], p.X[di], p.g[di], p.b[di], m0, M, wave, lane);
}

// ---------------- causal attention: wave per node, K/V staged in LDS ----------------
struct A3c { const float* q[3]; float* o[3]; int N[3]; int nend[3]; };

__global__ __launch_bounds__(256) void attn3(A3c p) {
    __shared__ float KV[4][2][8][136];   // [wave][K/V][t][h*17+j]
    int tid = threadIdx.x;
    int w = tid >> 6, lane = tid & 63;
    int g = blockIdx.x * 4 + w;
    int valid = g < p.nend[2];
    int n = 0, N = 1;
    const float* qkv = p.q[0]; float* o = p.o[0];
    if (valid) {
        int i = (g >= p.nend[0]) + (g >= p.nend[1]);
        n = g - (i ? p.nend[i - 1] : 0);
        N = p.N[i];
        qkv = p.q[i]; o = p.o[i];
        int half = lane >> 5, l5 = lane & 31;
        float* dp = &KV[w][half][0][(l5 >> 2) * 17 + (l5 & 3) * 4];
        for (int t8 = 0; t8 < 8; ++t8) {
            const float* rp = qkv + ((long)(t8 * N + n)) * 384 + 128 + half * 128 + l5 * 4;
            float4 vv = *(const float4*)rp;
            dp[0] = vv.x; dp[1] = vv.y; dp[2] = vv.z; dp[3] = vv.w;
            dp += 136;
        }
    }
    __syncthreads();
    if (!valid) return;
    int h = lane & 7, s = lane >> 3;
    const float* qp = qkv + ((long)(s * N + n)) * 384 + h * 16;
    float q[16];
    *(float4*)&q[0]  = *(const float4*)qp;
    *(float4*)&q[4]  = *(const float4*)(qp + 4);
    *(float4*)&q[8]  = *(const float4*)(qp + 8);
    *(float4*)&q[12] = *(const float4*)(qp + 12);
    const float* Kl = &KV[w][0][0][h * 17];
    const float* Vl = &KV[w][1][0][h * 17];
    float sc[8], mx = -1e30f;
#pragma unroll
    for (int m = 0; m < 8; ++m) {
        if (m <= s) {
            float dacc = 0.f;
#pragma unroll
            for (int j = 0; j < 16; ++j) dacc += q[j] * Kl[m * 136 + j];
            dacc *= 0.25f;
            sc[m] = dacc;
            mx = fmaxf(mx, dacc);
        }
    }
    float sum = 0.f;
#pragma unroll
    for (int m = 0; m < 8; ++m) if (m <= s) { sc[m] = expf(sc[m] - mx); sum += sc[m]; }
    float inv = 1.f / sum;
    float ov[16];
#pragma unroll
    for (int j = 0; j < 16; ++j) ov[j] = 0.f;
#pragma unroll
    for (int m = 0; m < 8; ++m) {
        if (m <= s) {
            float am = sc[m] * inv;
#pragma unroll
            for (int j = 0; j < 16; ++j) ov[j] += am * Vl[m * 136 + j];
        }
    }
    float* op = o + ((long)(s * N + n)) * 128 + h * 16;
    *(float4*)op        = *(float4*)&ov[0];
    *(float4*)(op + 4)  = *(float4*)&ov[4];
    *(float4*)(op + 8)  = *(float4*)&ov[8];
    *(float4*)(op + 12) = *(float4*)&ov[12];
}

// ---------------- scores via MFMA: C[t] = A_t @ B_t^T (bf16 inputs, fp32 out) ----------------
__global__ __launch_bounds__(256) void score_mfma(const float* __restrict__ A, const float* __restrict__ B,
                                                  float* __restrict__ out, int M, int Nn) {
    constexpr int PITCH = 136;
    __shared__ short Als[64 * PITCH];
    __shared__ short Bls[64 * PITCH];
    int t = blockIdx.z;
    const float* At = A + (long)t * M * kD;
    const float* Bt = B + (long)t * Nn * kD;
    float* Ot = out + (long)t * M * Nn;
    int bm = blockIdx.y * 64, bn = blockIdx.x * 64;
    int tid = threadIdx.x;
    int wave = tid >> 6, lane = tid & 63;
    int lrow = lane & 15, quad = lane >> 4;
    for (int ii = tid; ii < 64 * 64; ii += 256) {
        int r = ii >> 6, kp = ii & 63;
        float2 va = *(const float2*)&At[(long)(bm + r) * kD + 2 * kp];
        *(unsigned*)&Als[r * PITCH + 2 * kp] = (unsigned)f2b(va.x) | ((unsigned)f2b(va.y) << 16);
        float2 vb = make_float2(0.f, 0.f);
        if (bn + r < Nn) vb = *(const float2*)&Bt[(long)(bn + r) * kD + 2 * kp];
        *(unsigned*)&Bls[r * PITCH + 2 * kp] = (unsigned)f2b(vb.x) | ((unsigned)f2b(vb.y) << 16);
    }
    __syncthreads();
    short8 a[4];
#pragma unroll
    for (int kc = 0; kc < 4; ++kc)
        a[kc] = *(const short8*)&Als[(wave * 16 + lrow) * PITCH + kc * 32 + quad * 8];
#pragma unroll
    for (int nt = 0; nt < 4; ++nt) {
        floatx4 acc = (floatx4){0.f, 0.f, 0.f, 0.f};
#pragma unroll
        for (int kc = 0; kc < 4; ++kc) {
            short8 b = *(const short8*)&Bls[(nt * 16 + lrow) * PITCH + kc * 32 + quad * 8];
            acc = __builtin_amdgcn_mfma_f32_16x16x32_bf16(a[kc], b, acc, 0, 0, 0);
        }
        int col = bn + nt * 16 + lrow;
        if (col < Nn) {
#pragma unroll
            for (int r = 0; r < 4; ++r) {
                int row = bm + wave * 16 + quad * 4 + r;
                Ot[(long)row * Nn + col] = acc[r];
            }
        }
    }
}

// ---------------- labels scatter, both outputs ----------------
__global__ void label2(const int* __restrict__ s1, const int* __restrict__ d1, float* __restrict__ o1, int N1,
                       const int* __restrict__ s2, const int* __restrict__ d2, float* __restrict__ o2, int N2) {
    int idx = blockIdx.x * blockDim.x + threadIdx.x;
    if (idx >= 2 * kT * kE) return;
    int u = idx >> 17;
    int e = idx & (kT * kE - 1);
    int t = e >> 14;
    if (u == 0) { int s = s1[e], dd = d1[e]; o1[(long)t * kNADM * N1 + (long)s * N1 + dd] = 1.0f; }
    else        { int s = s2[e], dd = d2[e]; o2[(long)t * kNADM * N2 + (long)s * N2 + dd] = 1.0f; }
}

extern "C" void kernel_launch(void* const* d_in, const int* in_sizes, int n_in,
                              void* d_out, int out_size, void* d_ws, size_t ws_size,
                              hipStream_t stream) {
    const float* x_adm       = (const float*)d_in[0];
    const float* x_lab       = (const float*)d_in[1];
    const float* x_drug      = (const float*)d_in[2];
    const float* edge_x_did  = (const float*)d_in[3];
    const float* edge_x_took = (const float*)d_in[4];
    const float* w_proj_adm  = (const float*)d_in[5];
    const float* b_proj_adm  = (const float*)d_in[6];
    const float* w_proj_lab  = (const float*)d_in[7];
    const float* b_proj_lab  = (const float*)d_in[8];
    const float* w_proj_drug = (const float*)d_in[9];
    const float* b_proj_drug = (const float*)d_in[10];
    const float* w_proj_e    = (const float*)d_in[11];
    const float* b_proj_e    = (const float*)d_in[12];
    const float* w_proj_e4d  = (const float*)d_in[13];
    const float* b_proj_e4d  = (const float*)d_in[14];
    const float* emb_lab     = (const float*)d_in[15];
    const float* emb_drug    = (const float*)d_in[16];
    const float* gnn_w       = (const float*)d_in[17];
    const float* gnn_b       = (const float*)d_in[18];
    const float* dec_sa_in_w  = (const float*)d_in[19];
    const float* dec_sa_in_b  = (const float*)d_in[20];
    const float* dec_sa_out_w = (const float*)d_in[21];
    const float* dec_sa_out_b = (const float*)d_in[22];
    const float* dec_ca_in_w  = (const float*)d_in[23];
    const float* dec_ca_in_b  = (const float*)d_in[24];
    const float* dec_ca_out_w = (const float*)d_in[25];
    const float* dec_ca_out_b = (const float*)d_in[26];
    const float* dec_ff1_w    = (const float*)d_in[27];
    const float* dec_ff1_b    = (const float*)d_in[28];
    const float* dec_ff2_w    = (const float*)d_in[29];
    const float* dec_ff2_b    = (const float*)d_in[30];
    const float* dec_ln1_w    = (const float*)d_in[31];
    const float* dec_ln1_b    = (const float*)d_in[32];
    const float* dec_ln2_w    = (const float*)d_in[33];
    const float* dec_ln2_b    = (const float*)d_in[34];
    const float* dec_ln3_w    = (const float*)d_in[35];
    const float* dec_ln3_b    = (const float*)d_in[36];
    const int* node_id_lab  = (const int*)d_in[37];
    const int* node_id_drug = (const int*)d_in[38];
    const int* src_did      = (const int*)d_in[39];
    const int* dst_did      = (const int*)d_in[40];
    const int* src_took     = (const int*)d_in[41];
    const int* dst_took     = (const int*)d_in[42];
    const int* lbl_src_did  = (const int*)d_in[43];
    const int* lbl_dst_did  = (const int*)d_in[44];
    const int* lbl_src_took = (const int*)d_in[45];
    const int* lbl_dst_took = (const int*)d_in[46];

    float* out_f = (float*)d_out;
    const long SC1 = (long)kT * kNADM * kNLAB;    // 12,337,152
    const long SC2 = (long)kT * kNADM * kNDRUG;   // 70,352,896
    float* out_scores  = out_f;
    float* out_labels  = out_f + SC1;
    float* out_scores4 = out_f + 2 * SC1;
    float* out_labels4 = out_f + 2 * SC1 + SC2;

    // scratch arena inside d_out (scores4 + labels4 regions; both dead until the end)
    float* SCR = out_scores4;                     // 70.3M floats
    float* Sp  = out_labels4;
    const long SA_SZ = (long)kT * kNADM * kD;     // 2,097,152
    const long SL_SZ = (long)kT * kNLAB * kD;     //   771,072
    const long SD_SZ = (long)kT * kNDRUG * kD;    // 4,397,056
    float* Sa = Sp;
    float* Sl = Sa + SA_SZ;
    float* Sd = Sl + SL_SZ;                       // contiguous Sa|Sl|Sd
    short* pk_base = (short*)(Sp + 7265288);
    const long PS_SA_IN = 18L * 128 * 384;
    const long PS_SA_OUT = 18L * 128 * 128;
    const long PS_CA_IN = PS_SA_IN;
    const long PS_CA_OUT = PS_SA_OUT;
    const long PS_FF1 = 18L * 128 * 512;
    const long PS_FF2 = 18L * 512 * 128;
    short* pk_sa_in  = pk_base;
    short* pk_sa_out = pk_sa_in + PS_SA_IN;
    short* pk_ca_in  = pk_sa_out + PS_SA_OUT;
    short* pk_ca_out = pk_ca_in + PS_CA_IN;
    short* pk_ff1    = pk_ca_out + PS_CA_OUT;
    short* pk_ff2    = pk_ff1 + PS_FF1;

    // GNN-phase aliases in SCR
    float* h0a = SCR;
    float* h0l = h0a + (long)kNADM * kD;
    float* h0d = h0l + (long)kNLAB * kD;
    float* Ta  = h0d + (long)kNDRUG * kD;
    float* Tl  = Ta + SA_SZ;
    float* Td  = Tl + SL_SZ;
    float* msgA1 = Td + SD_SZ;
    float* msgA2 = msgA1 + SA_SZ;
    float* msgL  = msgA2 + SA_SZ;
    float* msgD  = msgL + SL_SZ;                  // ends ~17.54M floats
    // CSR scratch (ints) at SCR + 18M floats; dead before decoder writes bb there
    int* csr_cnt = (int*)(SCR + 18000000);
    int* csr_off = csr_cnt + CSR_SLOTS;
    int* csr_cur = csr_off + CSR_SLOTS;
    int* csr_lists = csr_cur + CSR_SLOTS;         // 4 * 131072 ints

    // decoder-phase aliases in SCR
    const int TNs[3] = {kT * kNADM, kT * kNLAB, kT * kNDRUG};   // 16384, 6024, 34352
    const int Ns_[3] = {kNADM, kNLAB, kNDRUG};
    const long rowsTot = (long)TNs[0] + TNs[1] + TNs[2];        // 56760
    const long roff[3] = {0, (long)TNs[0], (long)TNs[0] + TNs[1]};
    float* obase = SCR + rowsTot * 512;
    float* mbase = obase + rowsTot * 128;
    float* Xs[3] = {Sa, Sl, Sd};
    float* bb[3]; float* ob[3]; float* mb[3];
    for (int i = 0; i < 3; ++i) {
        bb[i] = SCR + roff[i] * 512;      // qkv buffer (rows x 384, alloc 512)
        ob[i] = obase + roff[i] * 128;    // attn output
        mb[i] = mbase + roff[i] * 128;    // memory (decoder input)
    }
    const int gB[3] = {(TNs[0] + 63) / 64, (TNs[1] + 63) / 64, (TNs[2] + 63) / 64}; // 256,95,537
    const int bend[3] = {gB[0], gB[0] + gB[1], gB[0] + gB[1] + gB[2]};              // 256,351,888
    const int gTot = bend[2];
    const int nend[3] = {kNADM, kNADM + kNLAB, kNADM + kNLAB + kNDRUG};             // 2048,2801,7095
    const int aBlk = (nend[2] + 3) / 4;                                             // 1774

    // ---- pack all decoder weights in one launch ----
    {
        PK6 pk;
        const float* Ws[6] = {dec_sa_in_w, dec_sa_out_w, dec_ca_in_w, dec_ca_out_w, dec_ff1_w, dec_ff2_w};
        short* outs[6] = {pk_sa_in, pk_sa_out, pk_ca_in, pk_ca_out, pk_ff1, pk_ff2};
        int Ks[6] = {128, 128, 128, 128, 128, 512};
        int Nss[6] = {384, 128, 384, 128, 512, 128};
        long tots[6] = {PS_SA_IN, PS_SA_OUT, PS_CA_IN, PS_CA_OUT, PS_FF1, PS_FF2};
        int cum = 0;
        for (int i = 0; i < 6; ++i) {
            pk.W[i] = Ws[i]; pk.out[i] = outs[i]; pk.K[i] = Ks[i]; pk.N[i] = Nss[i]; pk.tot[i] = tots[i];
            cum += (int)((tots[i] + 255) / 256);
            pk.bend[i] = cum;
        }
        pack6<<<cum, 256, 0, stream>>>(pk);
    }

    // ---- CSR build (topology fixed across layers) ----
    hipMemsetAsync((void*)csr_cnt, 0, (size_t)CSR_SLOTS * sizeof(int), stream);
    csr_hist<<<(4 * kT * kE + 255) / 256, 256, 0, stream>>>(dst_did, src_did, dst_took, src_took, csr_cnt);
    csr_scan<<<32, 256, 0, stream>>>(csr_cnt, csr_off, csr_cur);
    csr_scatter<<<(4 * kT * kE + 255) / 256, 256, 0, stream>>>(dst_did, src_did, dst_took, src_took,
                                                               csr_cur, csr_lists);

    // ---- node projections (merged) ----
    proj3<<<kNADM + kNLAB + kNDRUG, kD, 0, stream>>>(
        x_adm, w_proj_adm, b_proj_adm,
        x_lab, w_proj_lab, b_proj_lab, emb_lab, node_id_lab,
        x_drug, w_proj_drug, b_proj_drug, emb_drug, node_id_drug,
        h0a, h0l, h0d);

    // ---- GNN: 2 layers (gather, no atomics; layer-1 dense fuses PE + membuf copy) ----
    for (int l = 0; l < 2; ++l) {
        const float *ha, *hl, *hd;
        long sa, sl, sd;
        float *oa, *ol, *od;
        if (l == 0) { ha = h0a; hl = h0l; hd = h0d; sa = sl = sd = 0;
                      oa = Ta; ol = Tl; od = Td; }
        else        { ha = Ta; hl = Tl; hd = Td;
                      sa = (long)kNADM * kD; sl = (long)kNLAB * kD; sd = (long)kNDRUG * kD;
                      oa = Sa; ol = Sl; od = Sd; }
        GG gg;
        gg.ha = ha; gg.hl = hl; gg.hd = hd; gg.sa = sa; gg.sl = sl; gg.sd = sd;
        gg.exd = edge_x_did; gg.ext = edge_x_took;
        gg.we = w_proj_e; gg.be = b_proj_e; gg.we4 = w_proj_e4d; gg.be4 = b_proj_e4d;
        gg.srcd = src_did; gg.dstd = dst_did; gg.srct = src_took; gg.dstt = dst_took;
        gg.off = csr_off; gg.cnt = csr_cnt; gg.lists = csr_lists;
        gg.msgL = msgL; gg.msgA1 = msgA1; gg.msgD = msgD; gg.msgA2 = msgA2;
        csr_gather<<<CSR_SLOTS, 128, 0, stream>>>(gg);
        GD gd;
        gd.m1 = msgA1; gd.m2 = msgA2; gd.mL = msgL; gd.mD = msgD;
        gd.ha = ha; gd.hl = hl; gd.hd = hd;
        gd.sa = sa; gd.sl = sl; gd.sd = sd;
        gd.gw = gnn_w; gd.gb = gnn_b; gd.l = l;
        gd.oa = oa; gd.ol = ol; gd.od = od;
        gd.o2a = mb[0]; gd.o2l = mb[1]; gd.o2d = mb[2];
        gd.pe = (l == 1);
        gdense<<<1024 + 384 + 2152, 256, 0, stream>>>(gd);
    }

    // ---- decoders: all 3 batched per launch, 7 launches per layer ----
    for (int l = 0; l < kL; ++l) {
        long wi[3] = {(long)l, (long)(kL + l), (long)(2 * kL + l)};
        A3c at;
        for (int i = 0; i < 3; ++i) { at.q[i] = bb[i]; at.o[i] = ob[i]; at.N[i] = Ns_[i]; at.nend[i] = nend[i]; }

        // self-attention qkv (3 segments, NT=24)
        {
            G6 g;
            for (int i = 0; i < 3; ++i) {
                g.A[i] = Xs[i]; g.Bp[i] = pk_sa_in + wi[i] * 49152;
                g.bias[i] = dec_sa_in_b + wi[i] * 384; g.C[i] = bb[i];
                g.M[i] = TNs[i]; g.bend[i] = bend[i]; g.NT[i] = 24; g.ldc[i] = 384;
            }
            for (int i = 3; i < 6; ++i) { g.bend[i] = bend[2]; g.A[i] = g.A[2]; g.Bp[i] = g.Bp[2];
                g.bias[i] = g.bias[2]; g.C[i] = g.C[2]; g.M[i] = g.M[2]; g.NT[i] = 24; g.ldc[i] = 384; }
            gemm_rtN<<<gTot, 256, 0, stream>>>(g);
        }
        attn3<<<aBlk, 256, 0, stream>>>(at);
        // sa_out + residual + LN1
        {
            GL3 gl;
            for (int i = 0; i < 3; ++i) {
                gl.A[i] = ob[i]; gl.Bp[i] = pk_sa_out + wi[i] * 16384;
                gl.bias[i] = dec_sa_out_b + wi[i] * kD;
                gl.X[i] = Xs[i]; gl.g[i] = dec_ln1_w + wi[i] * kD; gl.b[i] = dec_ln1_b + wi[i] * kD;
                gl.M[i] = TNs[i]; gl.bend[i] = bend[i];
            }
            gemm_ln<<<gTot, 256, 0, stream>>>(gl);
        }
        // cross-attention qkv: q from X (NT=8) + kv from memory (NT=16), 6 segments in one launch
        {
            G6 g;
            for (int i = 0; i < 3; ++i) {
                g.A[i] = Xs[i]; g.Bp[i] = pk_ca_in + wi[i] * 49152;
                g.bias[i] = dec_ca_in_b + wi[i] * 384; g.C[i] = bb[i];
                g.M[i] = TNs[i]; g.bend[i] = bend[i]; g.NT[i] = 8; g.ldc[i] = 384;
            }
            for (int i = 0; i < 3; ++i) {
                g.A[3 + i] = mb[i]; g.Bp[3 + i] = pk_ca_in + wi[i] * 49152 + 16384;
                g.bias[3 + i] = dec_ca_in_b + wi[i] * 384 + 128; g.C[3 + i] = bb[i] + 128;
                g.M[3 + i] = TNs[i]; g.bend[3 + i] = bend[2] + bend[i]; g.NT[3 + i] = 16; g.ldc[3 + i] = 384;
            }
            gemm_rtN<<<2 * gTot, 256, 0, stream>>>(g);
        }
        attn3<<<aBlk, 256, 0, stream>>>(at);
        // ca_out + residual + LN2
        {
            GL3 gl;
            for (int i = 0; i < 3; ++i) {
                gl.A[i] = ob[i]; gl.Bp[i] = pk_ca_out + wi[i] * 16384;
                gl.bias[i] = dec_ca_out_b + wi[i] * kD;
                gl.X[i] = Xs[i]; gl.g[i] = dec_ln2_w + wi[i] * kD; gl.b[i] = dec_ln2_b + wi[i] * kD;
                gl.M[i] = TNs[i]; gl.bend[i] = bend[i];
            }
            gemm_ln<<<gTot, 256, 0, stream>>>(gl);
        }
        // fused FF1+FF2 + residual + LN3
        {
            GF3 gf;
            for (int i = 0; i < 3; ++i) {
                gf.A[i] = Xs[i];
                gf.B1[i] = pk_ff1 + wi[i] * 65536; gf.bias1[i] = dec_ff1_b + wi[i] * kFF;
                gf.B2[i] = pk_ff2 + wi[i] * 65536; gf.bias2[i] = dec_ff2_b + wi[i] * kD;
                gf.X[i] = Xs[i]; gf.g[i] = dec_ln3_w + wi[i] * kD; gf.b[i] = dec_ln3_b + wi[i] * kD;
                gf.M[i] = TNs[i]; gf.bend[i] = bend[i];
            }
            gemm_ff<<<gTot, 256, 0, stream>>>(gf);
        }
    }

    // scores via MFMA (bf16 inputs, fp32 accumulate/out)
    score_mfma<<<dim3((kNLAB + 63) / 64, kNADM / 64, kT), 256, 0, stream>>>(Sa, Sl, out_scores, kNADM, kNLAB);
    score_mfma<<<dim3((kNDRUG + 63) / 64, kNADM / 64, kT), 256, 0, stream>>>(Sa, Sd, out_scores4, kNADM, kNDRUG);
    // labels (memsets clobber scratch incl. Sa/Sl/Sd + packed weights, all dead now)
    hipMemsetAsync((void*)out_labels, 0, (size_t)SC1 * sizeof(float), stream);
    hipMemsetAsync((void*)out_labels4, 0, (size_t)SC2 * sizeof(float), stream);
    label2<<<(2 * kT * kE + 255) / 256, 256, 0, stream>>>(
        lbl_src_did, lbl_dst_did, out_labels, kNLAB,
        lbl_src_took, lbl_dst_took, out_labels4, kNDRUG);

    (void)in_sizes; (void)n_in; (void)out_size; (void)d_ws; (void)ws_size;
}